// Round 8
// baseline (267.272 us; speedup 1.0000x reference)
//
#include <hip/hip_runtime.h>

typedef __attribute__((ext_vector_type(8))) short short8;   // 8 bf16 = 4 VGPRs
typedef __attribute__((ext_vector_type(4))) float f32x4;    // MFMA accumulator

#define DEV static __device__ __forceinline__

DEV float bf2f(unsigned short b) { return __uint_as_float(((unsigned)b) << 16); }
DEV unsigned short f2bf(float f) {                          // round-to-nearest-even
  unsigned u = __float_as_uint(f);
  u += 0x7FFFu + ((u >> 16) & 1u);
  return (unsigned short)(u >> 16);
}

// ---------------- prep: f32 -> bf16 casts ----------------
__global__ __launch_bounds__(256) void cast_bf16(const float* __restrict__ src,
                                                 unsigned short* __restrict__ dst, int n4) {
  int i = blockIdx.x * 256 + threadIdx.x;
  if (i >= n4) return;
  float4 f = ((const float4*)src)[i];
  unsigned lo = (unsigned)f2bf(f.x) | ((unsigned)f2bf(f.y) << 16);
  unsigned hi = (unsigned)f2bf(f.z) | ((unsigned)f2bf(f.w) << 16);
  ((uint2*)dst)[i] = make_uint2(lo, hi);
}

__global__ __launch_bounds__(256) void cast_w4(
    const float* __restrict__ w0, const float* __restrict__ w1,
    const float* __restrict__ w2, const float* __restrict__ w3,
    unsigned short* __restrict__ o0, unsigned short* __restrict__ o1,
    unsigned short* __restrict__ o2, unsigned short* __restrict__ o3) {
  const int which = blockIdx.y;
  const float* s = (which == 0) ? w0 : (which == 1) ? w1 : (which == 2) ? w2 : w3;
  unsigned short* d = (which == 0) ? o0 : (which == 1) ? o1 : (which == 2) ? o2 : o3;
  const int i = blockIdx.x * 256 + threadIdx.x;
  float4 f = ((const float4*)s)[i];
  unsigned lo = (unsigned)f2bf(f.x) | ((unsigned)f2bf(f.y) << 16);
  unsigned hi = (unsigned)f2bf(f.z) | ((unsigned)f2bf(f.w) << 16);
  ((uint2*)d)[i] = make_uint2(lo, hi);
}

// ====== 256x256 bf16 GEMM, BK=32, TRIPLE-buffer LDS, 1 barrier + counted vmcnt/tile ======
// Per tile: stage t+2 -> buf[(j+2)%3]; 12 ds_read_b128 from buf[j%3]; 32 MFMA
// (compiler-interleaved, no clobbers inside body); VMC(4) retires tile t+1's loads,
// leaves t+2's 4 in flight (slack = 2 bodies >> HBM latency); one s_barrier.
// Swizzle: 16B slot ^= row&3 (4-way residual, under the MFMA floor).

DEV void stage32(const unsigned short* __restrict__ g, int row0, int ldk, int kcol,
                 unsigned short* lbuf, int wave, int lane) {
#pragma unroll
  for (int j = 0; j < 2; ++j) {
    const int rbase = j * 128 + wave * 16;              // wave-uniform
    const int row = rbase + (lane >> 2);
    const int k_src = (((lane & 3) ^ ((lane >> 2) & 3)) * 8);   // inverse swizzle
    const unsigned short* src = g + (size_t)(row0 + row) * ldk + kcol + k_src;
    unsigned short* dst = lbuf + rbase * 32;            // wave-uniform base, lane*16B auto
    __builtin_amdgcn_global_load_lds((const __attribute__((address_space(1))) void*)src,
                                     (__attribute__((address_space(3))) void*)dst, 16, 0, 0);
  }
}

#define BAR() do { asm volatile("" ::: "memory"); __builtin_amdgcn_s_barrier(); \
                   asm volatile("" ::: "memory"); } while (0)
#define VMC(n) asm volatile("s_waitcnt vmcnt(" #n ")" ::: "memory")

#define READ_A32(base) \
  _Pragma("unroll") for (int rg = 0; rg < 8; ++rg) \
    a[rg] = *(const short8*)((const char*)(base) + (wrow + rg * 16 + fr) * 64 + (kg16 ^ flip2));

#define READ_B32(base) \
  _Pragma("unroll") for (int cg = 0; cg < 4; ++cg) \
    bb[cg] = *(const short8*)((const char*)(base) + (wcol + cg * 16 + fr) * 64 + (kg16 ^ flip2));

#define MFMA32() \
  _Pragma("unroll") for (int rg = 0; rg < 8; ++rg) \
  _Pragma("unroll") for (int cg = 0; cg < 4; ++cg) \
    acc[rg][cg] = __builtin_amdgcn_mfma_f32_16x16x32_bf16(a[rg], bb[cg], acc[rg][cg], 0, 0, 0);

// body for tile j using compile-time buffer index BI
#define TB(j, BI) do { \
  const int j_ = (j); \
  const bool h2 = (j_ + 2 < NT), h1 = (j_ + 1 < NT); \
  if (h2) { \
    stage32(A,  brow, K, (j_ + 2) * 32, &As[(BI + 2) % 3][0], wave, lane); \
    stage32(Bt, bcol, K, (j_ + 2) * 32, &Bs[(BI + 2) % 3][0], wave, lane); \
  } \
  READ_A32(&As[BI][0]) \
  READ_B32(&Bs[BI][0]) \
  MFMA32() \
  if (h2)      { VMC(4); } \
  else if (h1) { VMC(0); } \
  BAR(); \
} while (0)

template<int EPI>
__global__ __launch_bounds__(512, 2) void gemm256(
    const unsigned short* __restrict__ A, const unsigned short* __restrict__ Bt,
    const float* __restrict__ bias0, const float* __restrict__ bias1,
    const float* __restrict__ bias2,
    float* __restrict__ outF,
    unsigned short* __restrict__ oQ, unsigned short* __restrict__ oK,
    unsigned short* __restrict__ oV,
    int M, int N, int K)
{
  __shared__ alignas(16) unsigned short As[3][8192];   // 48KB: [buf][row*32+k] swizzled
  __shared__ alignas(16) unsigned short Bs[3][8192];   // 48KB
  const int tid  = threadIdx.x;
  const int lane = tid & 63;
  const int wave = tid >> 6;
  const int wr = wave >> 2, wc = wave & 3;    // 2x4 wave grid; wave owns 128x64 output
  const int fr   = lane & 15;
  const int kg16 = (lane >> 4) * 16;          // k-group byte offset (K=32: 4 groups of 8)
  const int flip2 = (fr & 3) << 4;            // 2-bit XOR: 16B slot ^= row&3
  // bijective XCD swizzle (grid % 8 == 0 for both uses)
  const int nwg = gridDim.x, cpx = nwg >> 3, orig = blockIdx.x;
  const int logical = (orig & 7) * cpx + (orig >> 3);
  const int ntc = N >> 8;
  const int brow = (logical / ntc) << 8;
  const int bcol = (logical % ntc) << 8;
  const int NT = K >> 5;                      // 32 tiles at K=1024
  const int wrow = wr * 128, wcol = wc * 64;

  f32x4 acc[8][4] = {};
  short8 a[8], bb[4];

  // prologue: stage tile0 -> buf0, tile1 -> buf1; wait tile0 only
  stage32(A,  brow, K, 0,  &As[0][0], wave, lane);
  stage32(Bt, bcol, K, 0,  &Bs[0][0], wave, lane);
  stage32(A,  brow, K, 32, &As[1][0], wave, lane);
  stage32(Bt, bcol, K, 32, &Bs[1][0], wave, lane);
  VMC(4);
  BAR();

  for (int j = 0; j < NT; j += 3) {
    TB(j, 0);
    if (j + 1 < NT) TB(j + 1, 1);
    if (j + 2 < NT) TB(j + 2, 2);
  }

  // epilogue: C/D layout col=lane&15, row=(lane>>4)*4+q  [m89 verified]
  const int l4 = (lane >> 4) * 4;
#pragma unroll
  for (int rg = 0; rg < 8; ++rg) {
    const int row0 = brow + wrow + rg * 16 + l4;
#pragma unroll
    for (int cg = 0; cg < 4; ++cg) {
      const int col = bcol + wcol + cg * 16 + fr;
      if (EPI == 1) {
        const float bv_ = bias0[col];
#pragma unroll
        for (int q = 0; q < 4; ++q)
          outF[(size_t)(row0 + q) * N + col] = acc[rg][cg][q] + bv_;
      } else {
        const int sel = col >> 10;        // 0=q, 1=k, 2=v
        const int o = col & 1023;
        const float* bp = (sel == 0) ? bias0 : (sel == 1) ? bias1 : bias2;
        unsigned short* dstp = (sel == 0) ? oQ : (sel == 1) ? oK : oV;
        const float bv_ = bp[o];
#pragma unroll
        for (int q = 0; q < 4; ++q) {
          float val = acc[rg][cg][q] + bv_;
          if (sel < 2) val = (val > 0.f) ? (val + 1.f) : __expf(val);  // elu(x)+1
          dstp[(size_t)(row0 + q) * 1024 + o] = f2bf(val);
        }
      }
    }
  }
}

// ---------------- kv partials: grid 1024 = 64 bh x 16 chunks of 256 s ----------------
__global__ __launch_bounds__(256) void kv_agg(
    const unsigned short* __restrict__ kbuf, const unsigned short* __restrict__ vbuf,
    float* __restrict__ part_kv, float* __restrict__ part_ks)
{
  __shared__ alignas(16) unsigned short Ksm[16 * 64];
  __shared__ alignas(16) unsigned short Vsm[16 * 64];
  const int blk = blockIdx.x;           // 0..1023
  const int bh = blk >> 4, chunk = blk & 15;
  const int bb = bh >> 4, h = bh & 15;
  const int t = threadIdx.x;
  const int d0 = (t >> 4) * 4;
  const int e0 = (t & 15) * 4;
  const int ls = (t & 127) >> 3;
  const int lc = (t & 7) * 8;
  float acc[4][4] = {};
  float ks[4] = {0.f, 0.f, 0.f, 0.f};
  const int rb = bb * 4096 + chunk * 256;
  for (int ss = 0; ss < 256; ss += 16) {
    __syncthreads();
    const size_t ga = (size_t)(rb + ss + ls) * 1024 + h * 64 + lc;
    if (t < 128) *(uint4*)&Ksm[ls * 64 + lc] = *(const uint4*)&kbuf[ga];
    else         *(uint4*)&Vsm[ls * 64 + lc] = *(const uint4*)&vbuf[ga];
    __syncthreads();
#pragma unroll
    for (int i = 0; i < 16; ++i) {
      const unsigned ku0 = *(const unsigned*)&Ksm[i * 64 + d0];
      const unsigned ku1 = *(const unsigned*)&Ksm[i * 64 + d0 + 2];
      const unsigned vu0 = *(const unsigned*)&Vsm[i * 64 + e0];
      const unsigned vu1 = *(const unsigned*)&Vsm[i * 64 + e0 + 2];
      const float kk0 = __uint_as_float(ku0 << 16), kk1 = __uint_as_float(ku0 & 0xFFFF0000u);
      const float kk2 = __uint_as_float(ku1 << 16), kk3 = __uint_as_float(ku1 & 0xFFFF0000u);
      const float vv0 = __uint_as_float(vu0 << 16), vv1 = __uint_as_float(vu0 & 0xFFFF0000u);
      const float vv2 = __uint_as_float(vu1 << 16), vv3 = __uint_as_float(vu1 & 0xFFFF0000u);
      ks[0] += kk0; ks[1] += kk1; ks[2] += kk2; ks[3] += kk3;
      acc[0][0] += kk0 * vv0; acc[0][1] += kk0 * vv1; acc[0][2] += kk0 * vv2; acc[0][3] += kk0 * vv3;
      acc[1][0] += kk1 * vv0; acc[1][1] += kk1 * vv1; acc[1][2] += kk1 * vv2; acc[1][3] += kk1 * vv3;
      acc[2][0] += kk2 * vv0; acc[2][1] += kk2 * vv1; acc[2][2] += kk2 * vv2; acc[2][3] += kk2 * vv3;
      acc[3][0] += kk3 * vv0; acc[3][1] += kk3 * vv1; acc[3][2] += kk3 * vv2; acc[3][3] += kk3 * vv3;
    }
  }
#pragma unroll
  for (int r = 0; r < 4; ++r)
    *(float4*)&part_kv[((size_t)blk * 64 + d0 + r) * 64 + e0] =
        make_float4(acc[r][0], acc[r][1], acc[r][2], acc[r][3]);
  if ((t & 15) == 0) {
#pragma unroll
    for (int r = 0; r < 4; ++r) part_ks[blk * 64 + d0 + r] = ks[r];
  }
}

// ------- collapse partials -> kvTb bf16 [bh][e][d] + ksum f32 [bh][64] -------
__global__ __launch_bounds__(256) void kv_reduce(
    const float* __restrict__ part_kv, const float* __restrict__ part_ks,
    unsigned short* __restrict__ kvTb, float* __restrict__ ksf)
{
  const int bh = blockIdx.x;            // 64
  const int t = threadIdx.x;
#pragma unroll
  for (int i = 0; i < 16; ++i) {
    const int lin = i * 256 + t;        // lin = d*64+e
    float s = 0.f;
#pragma unroll
    for (int c = 0; c < 16; ++c) s += part_kv[((size_t)(bh * 16 + c)) * 4096 + lin];
    const int d = lin >> 6, e = lin & 63;
    kvTb[(size_t)bh * 4096 + e * 64 + d] = f2bf(s);   // transposed bf16
  }
  if (t < 64) {
    float s = 0.f;
#pragma unroll
    for (int c = 0; c < 16; ++c) s += part_ks[(bh * 16 + c) * 64 + t];
    ksf[bh * 64 + t] = s;
  }
}

// ---------------- attn via MFMA: C = q_tile(256x64) . kvT, normalized ----------------
__global__ __launch_bounds__(256) void attn_mfma(
    const unsigned short* __restrict__ qbuf,   // [rr][1024]
    const unsigned short* __restrict__ kvTb,   // [bh][e][d] bf16
    const float* __restrict__ ksf,             // [bh][64]
    unsigned short* __restrict__ attnb)        // [rr][1024]
{
  __shared__ alignas(16) unsigned short kvs[64 * 64];  // swizzled: 16B slot ^= e&7
  __shared__ float ks_lds[64];
  __shared__ float inv_lds[256];
  const int blk = blockIdx.x;           // 1024 = bh*16 + ntile
  const int bh = blk >> 4, ntile = blk & 15;
  const int bb = bh >> 4, h = bh & 15;
  const int t = threadIdx.x;
  const int lane = t & 63, w = t >> 6;
  const int fr = lane & 15, kg = lane >> 4;

  {
    const unsigned short* src = kvTb + (size_t)bh * 4096;
#pragma unroll
    for (int c = 0; c < 2; ++c) {
      const int slot = t * 2 + c;
      const int e = slot >> 3, sl = slot & 7;
      short8 v = *(const short8*)&src[e * 64 + sl * 8];
      *(short8*)&kvs[e * 64 + (sl ^ (e & 7)) * 8] = v;
    }
    if (t < 64) ks_lds[t] = ksf[bh * 64 + t];
  }

  const size_t gq = (size_t)bb * 4096 + ntile * 256 + w * 64;
  short8 a[4][2];
#pragma unroll
  for (int rg = 0; rg < 4; ++rg)
#pragma unroll
    for (int ks = 0; ks < 2; ++ks)
      a[rg][ks] = *(const short8*)&qbuf[(gq + rg * 16 + fr) * 1024 + h * 64 + ks * 32 + kg * 8];
  __syncthreads();

#pragma unroll
  for (int rg = 0; rg < 4; ++rg) {
    float p = 0.f;
#pragma unroll
    for (int ks = 0; ks < 2; ++ks)
#pragma unroll
      for (int j = 0; j < 8; ++j)
        p += bf2f(((const unsigned short*)&a[rg][ks])[j]) * ks_lds[ks * 32 + kg * 8 + j];
    p += __shfl_xor(p, 16);
    p += __shfl_xor(p, 32);
    if (kg == 0) inv_lds[w * 64 + rg * 16 + fr] = 1.f / (p + 1e-6f);
  }

  const int flip = (fr & 7) << 4;
  const int kq16 = kg * 16;
  short8 bf[4][2];
#pragma unroll
  for (int cg = 0; cg < 4; ++cg)
#pragma unroll
    for (int ks = 0; ks < 2; ++ks)
      bf[cg][ks] = *(const short8*)((const char*)kvs + (cg * 16 + fr) * 128 + ((ks * 64 + kq16) ^ flip));
  f32x4 acc[4][4] = {};
#pragma unroll
  for (int rg = 0; rg < 4; ++rg)
#pragma unroll
    for (int cg = 0; cg < 4; ++cg)
#pragma unroll
      for (int ks = 0; ks < 2; ++ks)
        acc[rg][cg] = __builtin_amdgcn_mfma_f32_16x16x32_bf16(a[rg][ks], bf[cg][ks], acc[rg][cg], 0, 0, 0);

  __syncthreads();

#pragma unroll
  for (int rg = 0; rg < 4; ++rg)
#pragma unroll
    for (int cg = 0; cg < 4; ++cg)
#pragma unroll
      for (int q = 0; q < 4; ++q) {
        const int r = rg * 16 + kg * 4 + q;
        const float iv = inv_lds[w * 64 + r];
        attnb[(gq + r) * 1024 + h * 64 + cg * 16 + fr] = f2bf(acc[rg][cg][q] * iv);
      }
}

extern "C" void kernel_launch(void* const* d_in, const int* in_sizes, int n_in,
                              void* d_out, int out_size, void* d_ws, size_t ws_size,
                              hipStream_t stream)
{
  const float* query = (const float*)d_in[0];
  const float* Wq = (const float*)d_in[1];
  const float* bq = (const float*)d_in[2];
  const float* Wk = (const float*)d_in[3];
  const float* bk = (const float*)d_in[4];
  const float* Wv = (const float*)d_in[5];
  const float* bv = (const float*)d_in[6];
  const float* Wo = (const float*)d_in[7];
  const float* bo = (const float*)d_in[8];
  float* out = (float*)d_out;

  const int M = in_sizes[0] / 1024;               // 16384 rows (B*N)

  char* ws = (char*)d_ws;
  unsigned short* qbf   = (unsigned short*)(ws);              // 32MB (dead after QKV)
  unsigned short* attnb = (unsigned short*)(ws);              // reuse
  unsigned short* wqkv  = (unsigned short*)(ws + 33554432);   // 6MB
  unsigned short* wobf  = (unsigned short*)(ws + 39845888);   // 2MB
  unsigned short* phiq  = (unsigned short*)(ws + 41943040);   // 32MB [rr][1024]
  unsigned short* phik  = (unsigned short*)(ws + 75497472);   // 32MB
  unsigned short* vbf   = (unsigned short*)(ws + 109051904);  // 32MB
  float*          pkv   = (float*)(ws + 142606336);           // 16MB [1024][64][64]
  float*          pks   = (float*)(ws + 159383552);           // 256KB
  unsigned short* kvTb  = (unsigned short*)(ws + 159645696);  // 512KB [64][64][64]
  float*          ksf   = (float*)(ws + 160169984);           // 16KB

  cast_bf16<<<(M * 1024 / 4 + 255) / 256, 256, 0, stream>>>(query, qbf, M * 1024 / 4);
  cast_w4<<<dim3(1024, 4), 256, 0, stream>>>(Wq, Wk, Wv, Wo,
                                             wqkv, wqkv + 1048576, wqkv + 2097152, wobf);

  gemm256<0><<<dim3((M / 256) * (3072 / 256)), 512, 0, stream>>>(
      qbf, wqkv, bq, bk, bv, nullptr, phiq, phik, vbf, M, 3072, 1024);

  kv_agg<<<1024, 256, 0, stream>>>(phik, vbf, pkv, pks);
  kv_reduce<<<64, 256, 0, stream>>>(pkv, pks, kvTb, ksf);
  attn_mfma<<<1024, 256, 0, stream>>>(phiq, kvTb, ksf, attnb);

  gemm256<1><<<dim3((M / 256) * (1024 / 256)), 512, 0, stream>>>(
      attnb, wobf, bo, nullptr, nullptr, out, nullptr, nullptr, nullptr, M, 1024, 1024);
}

// Round 13
// 249.197 us; speedup vs baseline: 1.0725x; 1.0725x over previous
//
#include <hip/hip_runtime.h>

typedef __attribute__((ext_vector_type(8))) short short8;   // 8 bf16 = 4 VGPRs
typedef __attribute__((ext_vector_type(4))) float f32x4;    // MFMA accumulator

#define DEV static __device__ __forceinline__

DEV float bf2f(unsigned short b) { return __uint_as_float(((unsigned)b) << 16); }
DEV unsigned short f2bf(float f) {                          // round-to-nearest-even
  unsigned u = __float_as_uint(f);
  u += 0x7FFFu + ((u >> 16) & 1u);
  return (unsigned short)(u >> 16);
}

// ---------------- prep: all f32 -> bf16 casts in ONE launch ----------------
// query: 16384x1024 f32 = 4,194,304 float4 -> 16384 blocks of 256
// weights: 4 x 1024x1024 f32 = 262,144 float4 each -> 4 x 1024 blocks
__global__ __launch_bounds__(256) void cast_all(
    const float* __restrict__ q,
    const float* __restrict__ w0, const float* __restrict__ w1,
    const float* __restrict__ w2, const float* __restrict__ w3,
    unsigned short* __restrict__ oq,
    unsigned short* __restrict__ o0, unsigned short* __restrict__ o1,
    unsigned short* __restrict__ o2, unsigned short* __restrict__ o3) {
  const int b = blockIdx.x;
  const float* s;
  unsigned short* d;
  int i;
  if (b < 16384) {                        // query
    s = q; d = oq; i = b * 256 + threadIdx.x;
  } else {                                // weights
    const int wsel = (b - 16384) >> 10, wb = (b - 16384) & 1023;
    s = (wsel == 0) ? w0 : (wsel == 1) ? w1 : (wsel == 2) ? w2 : w3;
    d = (wsel == 0) ? o0 : (wsel == 1) ? o1 : (wsel == 2) ? o2 : o3;
    i = wb * 256 + threadIdx.x;
  }
  float4 f = ((const float4*)s)[i];
  unsigned lo = (unsigned)f2bf(f.x) | ((unsigned)f2bf(f.y) << 16);
  unsigned hi = (unsigned)f2bf(f.z) | ((unsigned)f2bf(f.w) << 16);
  ((uint2*)d)[i] = make_uint2(lo, hi);
}

// ============== 256x256 8-phase bf16 GEMM, S2 skeleton + hoisted ds_reads ==============
// b1-read at P1 tail, a(1)-read at P2 tail (cross one barrier window before their
// lgkmcnt(0)); next-tile quadrant-0 reads at P4 tail after VMC (pattern passed in r4-r7).
// sched_barrier(0) pins hoisted reads after the MFMA cluster (no register double-buffer).

DEV void stage_half(const unsigned short* __restrict__ g, int row0, int ldk, int kcol,
                    unsigned short* lbuf, int half, int wave, int lane) {
#pragma unroll
  for (int j = 0; j < 2; ++j) {
    const int row_lin = half * 128 + j * 64 + wave * 8 + (lane >> 3);
    const int k_src = (((lane & 7) ^ ((lane >> 3) & 7)) * 8);  // 16B slot ^= row&7
    const unsigned short* src = g + (size_t)(row0 + row_lin) * ldk + kcol + k_src;
    unsigned short* dst = lbuf + half * 8192 + j * 4096 + wave * 512;  // wave-uniform base
    __builtin_amdgcn_global_load_lds((const __attribute__((address_space(1))) void*)src,
                                     (__attribute__((address_space(3))) void*)dst, 16, 0, 0);
  }
}

#define BAR() do { asm volatile("" ::: "memory"); __builtin_amdgcn_s_barrier(); \
                   asm volatile("" ::: "memory"); } while (0)
#define LGKM0() asm volatile("s_waitcnt lgkmcnt(0)" ::: "memory")
#define VMC(n) asm volatile("s_waitcnt vmcnt(" #n ")" ::: "memory")
#define SCHED0() __builtin_amdgcn_sched_barrier(0)

#define READ_Aset(dst, qr, base) \
  _Pragma("unroll") for (int i4 = 0; i4 < 4; ++i4) \
  _Pragma("unroll") for (int ks = 0; ks < 2; ++ks) { \
    const int r_ = wrow + (qr) * 64 + i4 * 16 + fr; \
    dst[i4][ks] = *(const short8*)((base) + r_ * 128 + ((ks * 64 + kq16) ^ flip)); }

#define READ_Bset(dst, qc, base) \
  _Pragma("unroll") for (int c2 = 0; c2 < 2; ++c2) \
  _Pragma("unroll") for (int ks = 0; ks < 2; ++ks) { \
    const int c_ = wcol + (qc) * 32 + c2 * 16 + fr; \
    dst[c2][ks] = *(const short8*)((base) + c_ * 128 + ((ks * 64 + kq16) ^ flip)); }

#define MMQ(qr, qc, A_, B_) \
  _Pragma("unroll") for (int i4 = 0; i4 < 4; ++i4) \
  _Pragma("unroll") for (int c2 = 0; c2 < 2; ++c2) \
  _Pragma("unroll") for (int ks = 0; ks < 2; ++ks) \
    acc[(qr) * 4 + i4][(qc) * 2 + c2] = __builtin_amdgcn_mfma_f32_16x16x32_bf16( \
        A_[i4][ks], B_[c2][ks], acc[(qr) * 4 + i4][(qc) * 2 + c2], 0, 0, 0);

template<int EPI>
__global__ __launch_bounds__(512, 2) void gemm256(
    const unsigned short* __restrict__ A, const unsigned short* __restrict__ Bt,
    const float* __restrict__ bias0, const float* __restrict__ bias1,
    const float* __restrict__ bias2,
    float* __restrict__ outF,
    unsigned short* __restrict__ oQ, unsigned short* __restrict__ oK,
    unsigned short* __restrict__ oV,
    int M, int N, int K)
{
  __shared__ alignas(16) unsigned short As[2][16384];
  __shared__ alignas(16) unsigned short Bs[2][16384];
  const int tid  = threadIdx.x;
  const int lane = tid & 63;
  const int wave = tid >> 6;
  const int wr = wave >> 2, wc = wave & 3;    // 2x4 wave grid; wave owns 128x64 output
  const int fr   = lane & 15;
  const int kq16 = (lane >> 4) * 16;
  const int flip = (fr & 7) << 4;             // 3-bit XOR: 16B slot ^= row&7
  const int nwg = gridDim.x, cpx = nwg >> 3, orig = blockIdx.x;
  const int logical = (orig & 7) * cpx + (orig >> 3);
  const int ntc = N >> 8;
  const int brow = (logical / ntc) << 8;
  const int bcol = (logical % ntc) << 8;
  const int NT = K >> 6;
  const int wrow = wr * 128, wcol = wc * 64;

  f32x4 acc[8][4] = {};
  short8 a[4][2], b0[2][2], b1[2][2];

  // prologue: tile0 {A0,A1,B0,B1}, tile1 {B0,A0}
  stage_half(A,  brow, K, 0, &As[0][0], 0, wave, lane);
  stage_half(A,  brow, K, 0, &As[0][0], 1, wave, lane);
  stage_half(Bt, bcol, K, 0, &Bs[0][0], 0, wave, lane);
  stage_half(Bt, bcol, K, 0, &Bs[0][0], 1, wave, lane);
  if (NT > 1) {
    stage_half(Bt, bcol, K, 64, &Bs[1][0], 0, wave, lane);
    stage_half(A,  brow, K, 64, &As[1][0], 0, wave, lane);
    VMC(4);
  } else {
    VMC(0);
  }
  BAR();
  // pre-read tile0 quadrant-0 fragments
  READ_Aset(a, 0, (const char*)&As[0][0])
  READ_Bset(b0, 0, (const char*)&Bs[0][0])

  for (int t = 0; t < NT; ++t) {
    const int cur = t & 1;
    const char* Ac = (const char*)&As[cur][0];
    const char* Bc = (const char*)&Bs[cur][0];
    const char* An = (const char*)&As[cur ^ 1][0];
    const char* Bn = (const char*)&Bs[cur ^ 1][0];
    const int k1 = (t + 1) << 6, k2 = (t + 2) << 6;
    const bool h1 = t < NT - 1, h2 = t < NT - 2;

    // ---- P1: MM(0,0) a*b0; hoisted read b1(cur); stage (t+1).B1 -> NXT ----
    if (h1) stage_half(Bt, bcol, K, k1, &Bs[cur ^ 1][0], 1, wave, lane);
    BAR(); LGKM0();
    __builtin_amdgcn_s_setprio(1);
    MMQ(0, 0, a, b0)
    __builtin_amdgcn_s_setprio(0);
    SCHED0();
    READ_Bset(b1, 1, Bc)
    BAR();

    // ---- P2: MM(0,1) a*b1; hoisted read a <- A(1)(cur); stage (t+1).A1 -> NXT ----
    if (h1) stage_half(A, brow, K, k1, &As[cur ^ 1][0], 1, wave, lane);
    BAR(); LGKM0();
    __builtin_amdgcn_s_setprio(1);
    MMQ(0, 1, a, b1)
    __builtin_amdgcn_s_setprio(0);
    SCHED0();
    READ_Aset(a, 1, Ac)
    BAR();

    // ---- P3: MM(1,0) a*b0; stage (t+2).B0 -> CUR (B reads of CUR done by P2) ----
    if (h2) stage_half(Bt, bcol, K, k2, &Bs[cur][0], 0, wave, lane);
    BAR(); LGKM0();
    __builtin_amdgcn_s_setprio(1);
    MMQ(1, 0, a, b0)
    __builtin_amdgcn_s_setprio(0);
    BAR();

    // ---- P4: MM(1,1) a*b1; VMC; trailing reads a,b0 <- next tile (NXT) ----
    if (h2) stage_half(A, brow, K, k2, &As[cur][0], 0, wave, lane);
    BAR();
    __builtin_amdgcn_s_setprio(1);
    MMQ(1, 1, a, b1)
    __builtin_amdgcn_s_setprio(0);
    if (h2)      { VMC(4); }   // retires all of tile t+1; (t+2) halves stay in flight
    else if (h1) { VMC(0); }
    SCHED0();
    if (h1) { READ_Aset(a, 0, An) READ_Bset(b0, 0, Bn) }
    BAR();
  }

  // epilogue: C/D layout col=lane&15, row=(lane>>4)*4+q  [m89 verified]
  const int l4 = (lane >> 4) * 4;
#pragma unroll
  for (int rg = 0; rg < 8; ++rg) {
    const int row0 = brow + wrow + rg * 16 + l4;
#pragma unroll
    for (int cg = 0; cg < 4; ++cg) {
      const int col = bcol + wcol + cg * 16 + fr;
      if (EPI == 1) {
        const float bb = bias0[col];
#pragma unroll
        for (int q = 0; q < 4; ++q)
          outF[(size_t)(row0 + q) * N + col] = acc[rg][cg][q] + bb;
      } else {
        const int sel = col >> 10;        // 0=q, 1=k, 2=v
        const int o = col & 1023;
        const float* bp = (sel == 0) ? bias0 : (sel == 1) ? bias1 : bias2;
        unsigned short* dstp = (sel == 0) ? oQ : (sel == 1) ? oK : oV;
        const float bb = bp[o];
#pragma unroll
        for (int q = 0; q < 4; ++q) {
          float val = acc[rg][cg][q] + bb;
          if (sel < 2) val = (val > 0.f) ? (val + 1.f) : __expf(val);  // elu(x)+1
          dstp[(size_t)(row0 + q) * 1024 + o] = f2bf(val);
        }
      }
    }
  }
}

// ---------------- kv partials: grid 1024 = 64 bh x 16 chunks of 256 s ----------------
__global__ __launch_bounds__(256) void kv_agg(
    const unsigned short* __restrict__ kbuf, const unsigned short* __restrict__ vbuf,
    float* __restrict__ part_kv, float* __restrict__ part_ks)
{
  __shared__ alignas(16) unsigned short Ksm[16 * 64];
  __shared__ alignas(16) unsigned short Vsm[16 * 64];
  const int blk = blockIdx.x;           // 0..1023
  const int bh = blk >> 4, chunk = blk & 15;
  const int bb = bh >> 4, h = bh & 15;
  const int t = threadIdx.x;
  const int d0 = (t >> 4) * 4;
  const int e0 = (t & 15) * 4;
  const int ls = (t & 127) >> 3;
  const int lc = (t & 7) * 8;
  float acc[4][4] = {};
  float ks[4] = {0.f, 0.f, 0.f, 0.f};
  const int rb = bb * 4096 + chunk * 256;
  for (int ss = 0; ss < 256; ss += 16) {
    __syncthreads();
    const size_t ga = (size_t)(rb + ss + ls) * 1024 + h * 64 + lc;
    if (t < 128) *(uint4*)&Ksm[ls * 64 + lc] = *(const uint4*)&kbuf[ga];
    else         *(uint4*)&Vsm[ls * 64 + lc] = *(const uint4*)&vbuf[ga];
    __syncthreads();
#pragma unroll
    for (int i = 0; i < 16; ++i) {
      const unsigned ku0 = *(const unsigned*)&Ksm[i * 64 + d0];
      const unsigned ku1 = *(const unsigned*)&Ksm[i * 64 + d0 + 2];
      const unsigned vu0 = *(const unsigned*)&Vsm[i * 64 + e0];
      const unsigned vu1 = *(const unsigned*)&Vsm[i * 64 + e0 + 2];
      const float kk0 = __uint_as_float(ku0 << 16), kk1 = __uint_as_float(ku0 & 0xFFFF0000u);
      const float kk2 = __uint_as_float(ku1 << 16), kk3 = __uint_as_float(ku1 & 0xFFFF0000u);
      const float vv0 = __uint_as_float(vu0 << 16), vv1 = __uint_as_float(vu0 & 0xFFFF0000u);
      const float vv2 = __uint_as_float(vu1 << 16), vv3 = __uint_as_float(vu1 & 0xFFFF0000u);
      ks[0] += kk0; ks[1] += kk1; ks[2] += kk2; ks[3] += kk3;
      acc[0][0] += kk0 * vv0; acc[0][1] += kk0 * vv1; acc[0][2] += kk0 * vv2; acc[0][3] += kk0 * vv3;
      acc[1][0] += kk1 * vv0; acc[1][1] += kk1 * vv1; acc[1][2] += kk1 * vv2; acc[1][3] += kk1 * vv3;
      acc[2][0] += kk2 * vv0; acc[2][1] += kk2 * vv1; acc[2][2] += kk2 * vv2; acc[2][3] += kk2 * vv3;
      acc[3][0] += kk3 * vv0; acc[3][1] += kk3 * vv1; acc[3][2] += kk3 * vv2; acc[3][3] += kk3 * vv3;
    }
  }
#pragma unroll
  for (int r = 0; r < 4; ++r)
    *(float4*)&part_kv[((size_t)blk * 64 + d0 + r) * 64 + e0] =
        make_float4(acc[r][0], acc[r][1], acc[r][2], acc[r][3]);
  if ((t & 15) == 0) {
#pragma unroll
    for (int r = 0; r < 4; ++r) part_ks[blk * 64 + d0 + r] = ks[r];
  }
}

// ------- collapse partials -> kvTb bf16 [bh][e][d] + ksum f32 [bh][64] -------
__global__ __launch_bounds__(256) void kv_reduce(
    const float* __restrict__ part_kv, const float* __restrict__ part_ks,
    unsigned short* __restrict__ kvTb, float* __restrict__ ksf)
{
  const int bh = blockIdx.x;            // 64
  const int t = threadIdx.x;
#pragma unroll
  for (int i = 0; i < 16; ++i) {
    const int lin = i * 256 + t;        // lin = d*64+e
    float s = 0.f;
#pragma unroll
    for (int c = 0; c < 16; ++c) s += part_kv[((size_t)(bh * 16 + c)) * 4096 + lin];
    const int d = lin >> 6, e = lin & 63;
    kvTb[(size_t)bh * 4096 + e * 64 + d] = f2bf(s);   // transposed bf16
  }
  if (t < 64) {
    float s = 0.f;
#pragma unroll
    for (int c = 0; c < 16; ++c) s += part_ks[(bh * 16 + c) * 64 + t];
    ksf[bh * 64 + t] = s;
  }
}

// ---------------- attn via MFMA: C = q_tile(256x64) . kvT, normalized ----------------
__global__ __launch_bounds__(256) void attn_mfma(
    const unsigned short* __restrict__ qbuf,   // [rr][1024]
    const unsigned short* __restrict__ kvTb,   // [bh][e][d] bf16
    const float* __restrict__ ksf,             // [bh][64]
    unsigned short* __restrict__ attnb)        // [rr][1024]
{
  __shared__ alignas(16) unsigned short kvs[64 * 64];  // swizzled: 16B slot ^= e&7
  __shared__ float ks_lds[64];
  __shared__ float inv_lds[256];
  const int blk = blockIdx.x;           // 1024 = bh*16 + ntile
  const int bh = blk >> 4, ntile = blk & 15;
  const int bb = bh >> 4, h = bh & 15;
  const int t = threadIdx.x;
  const int lane = t & 63, w = t >> 6;
  const int fr = lane & 15, kg = lane >> 4;

  {
    const unsigned short* src = kvTb + (size_t)bh * 4096;
#pragma unroll
    for (int c = 0; c < 2; ++c) {
      const int slot = t * 2 + c;
      const int e = slot >> 3, sl = slot & 7;
      short8 v = *(const short8*)&src[e * 64 + sl * 8];
      *(short8*)&kvs[e * 64 + (sl ^ (e & 7)) * 8] = v;
    }
    if (t < 64) ks_lds[t] = ksf[bh * 64 + t];
  }

  const size_t gq = (size_t)bb * 4096 + ntile * 256 + w * 64;
  short8 a[4][2];
#pragma unroll
  for (int rg = 0; rg < 4; ++rg)
#pragma unroll
    for (int ks = 0; ks < 2; ++ks)
      a[rg][ks] = *(const short8*)&qbuf[(gq + rg * 16 + fr) * 1024 + h * 64 + ks * 32 + kg * 8];
  __syncthreads();

#pragma unroll
  for (int rg = 0; rg < 4; ++rg) {
    float p = 0.f;
#pragma unroll
    for (int ks = 0; ks < 2; ++ks)
#pragma unroll
      for (int j = 0; j < 8; ++j)
        p += bf2f(((const unsigned short*)&a[rg][ks])[j]) * ks_lds[ks * 32 + kg * 8 + j];
    p += __shfl_xor(p, 16);
    p += __shfl_xor(p, 32);
    if (kg == 0) inv_lds[w * 64 + rg * 16 + fr] = 1.f / (p + 1e-6f);
  }

  const int flip = (fr & 7) << 4;
  const int kq16 = kg * 16;
  short8 bf[4][2];
#pragma unroll
  for (int cg = 0; cg < 4; ++cg)
#pragma unroll
    for (int ks = 0; ks < 2; ++ks)
      bf[cg][ks] = *(const short8*)((const char*)kvs + (cg * 16 + fr) * 128 + ((ks * 64 + kq16) ^ flip));
  f32x4 acc[4][4] = {};
#pragma unroll
  for (int rg = 0; rg < 4; ++rg)
#pragma unroll
    for (int cg = 0; cg < 4; ++cg)
#pragma unroll
      for (int ks = 0; ks < 2; ++ks)
        acc[rg][cg] = __builtin_amdgcn_mfma_f32_16x16x32_bf16(a[rg][ks], bf[cg][ks], acc[rg][cg], 0, 0, 0);

  __syncthreads();

#pragma unroll
  for (int rg = 0; rg < 4; ++rg)
#pragma unroll
    for (int cg = 0; cg < 4; ++cg)
#pragma unroll
      for (int q = 0; q < 4; ++q) {
        const int r = rg * 16 + kg * 4 + q;
        const float iv = inv_lds[w * 64 + r];
        attnb[(gq + r) * 1024 + h * 64 + cg * 16 + fr] = f2bf(acc[rg][cg][q] * iv);
      }
}

extern "C" void kernel_launch(void* const* d_in, const int* in_sizes, int n_in,
                              void* d_out, int out_size, void* d_ws, size_t ws_size,
                              hipStream_t stream)
{
  const float* query = (const float*)d_in[0];
  const float* Wq = (const float*)d_in[1];
  const float* bq = (const float*)d_in[2];
  const float* Wk = (const float*)d_in[3];
  const float* bk = (const float*)d_in[4];
  const float* Wv = (const float*)d_in[5];
  const float* bv = (const float*)d_in[6];
  const float* Wo = (const float*)d_in[7];
  const float* bo = (const float*)d_in[8];
  float* out = (float*)d_out;

  const int M = in_sizes[0] / 1024;               // 16384 rows (B*N)

  char* ws = (char*)d_ws;
  unsigned short* qbf   = (unsigned short*)(ws);              // 32MB (dead after QKV)
  unsigned short* attnb = (unsigned short*)(ws);              // reuse
  unsigned short* wqkv  = (unsigned short*)(ws + 33554432);   // 6MB
  unsigned short* wobf  = (unsigned short*)(ws + 39845888);   // 2MB
  unsigned short* phiq  = (unsigned short*)(ws + 41943040);   // 32MB [rr][1024]
  unsigned short* phik  = (unsigned short*)(ws + 75497472);   // 32MB
  unsigned short* vbf   = (unsigned short*)(ws + 109051904);  // 32MB
  float*          pkv   = (float*)(ws + 142606336);           // 16MB [1024][64][64]
  float*          pks   = (float*)(ws + 159383552);           // 256KB
  unsigned short* kvTb  = (unsigned short*)(ws + 159645696);  // 512KB [64][64][64]
  float*          ksf   = (float*)(ws + 160169984);           // 16KB

  // 1) all casts, one launch (16384 query blocks + 4096 weight blocks)
  cast_all<<<20480, 256, 0, stream>>>(query, Wq, Wk, Wv, Wo,
                                      qbf, wqkv, wqkv + 1048576, wqkv + 2097152, wobf);

  // 2) fused QKV projection + feature map (grid 768 = 96/XCD)
  gemm256<0><<<dim3((M / 256) * (3072 / 256)), 512, 0, stream>>>(
      qbf, wqkv, bq, bk, bv, nullptr, phiq, phik, vbf, M, 3072, 1024);

  kv_agg<<<1024, 256, 0, stream>>>(phik, vbf, pkv, pks);
  kv_reduce<<<64, 256, 0, stream>>>(pkv, pks, kvTb, ksf);
  attn_mfma<<<1024, 256, 0, stream>>>(phiq, kvTb, ksf, attnb);

  // 6) output projection -> fp32 d_out (grid 256 = 32/XCD)
  gemm256<1><<<dim3((M / 256) * (1024 / 256)), 512, 0, stream>>>(
      attnb, wobf, bo, nullptr, nullptr, out, nullptr, nullptr, nullptr, M, 1024, 1024);
}

// Round 14
// 241.490 us; speedup vs baseline: 1.1068x; 1.0319x over previous
//
#include <hip/hip_runtime.h>

typedef __attribute__((ext_vector_type(8))) short short8;   // 8 bf16 = 4 VGPRs
typedef __attribute__((ext_vector_type(4))) float f32x4;    // MFMA accumulator

#define DEV static __device__ __forceinline__

DEV float bf2f(unsigned short b) { return __uint_as_float(((unsigned)b) << 16); }
DEV unsigned short f2bf(float f) {                          // round-to-nearest-even
  unsigned u = __float_as_uint(f);
  u += 0x7FFFu + ((u >> 16) & 1u);
  return (unsigned short)(u >> 16);
}

// ---------------- prep: all f32 -> bf16 casts in ONE launch ----------------
// query: 16384x1024 f32 = 4,194,304 float4 -> 16384 blocks of 256
// weights: 4 x 1024x1024 f32 = 262,144 float4 each -> 4 x 1024 blocks
__global__ __launch_bounds__(256) void cast_all(
    const float* __restrict__ q,
    const float* __restrict__ w0, const float* __restrict__ w1,
    const float* __restrict__ w2, const float* __restrict__ w3,
    unsigned short* __restrict__ oq,
    unsigned short* __restrict__ o0, unsigned short* __restrict__ o1,
    unsigned short* __restrict__ o2, unsigned short* __restrict__ o3) {
  const int b = blockIdx.x;
  const float* s;
  unsigned short* d;
  int i;
  if (b < 16384) {                        // query
    s = q; d = oq; i = b * 256 + threadIdx.x;
  } else {                                // weights
    const int wsel = (b - 16384) >> 10, wb = (b - 16384) & 1023;
    s = (wsel == 0) ? w0 : (wsel == 1) ? w1 : (wsel == 2) ? w2 : w3;
    d = (wsel == 0) ? o0 : (wsel == 1) ? o1 : (wsel == 2) ? o2 : o3;
    i = wb * 256 + threadIdx.x;
  }
  float4 f = ((const float4*)s)[i];
  unsigned lo = (unsigned)f2bf(f.x) | ((unsigned)f2bf(f.y) << 16);
  unsigned hi = (unsigned)f2bf(f.z) | ((unsigned)f2bf(f.w) << 16);
  ((uint2*)d)[i] = make_uint2(lo, hi);
}

// ============== 256x256 8-phase bf16 GEMM (r7 schedule — best measured) ==============
DEV void stage_half(const unsigned short* __restrict__ g, int row0, int ldk, int kcol,
                    unsigned short* lbuf, int half, int wave, int lane) {
#pragma unroll
  for (int j = 0; j < 2; ++j) {
    const int row_lin = half * 128 + j * 64 + wave * 8 + (lane >> 3);
    const int k_src = (((lane & 7) ^ ((lane >> 3) & 7)) * 8);  // 16B slot ^= row&7
    const unsigned short* src = g + (size_t)(row0 + row_lin) * ldk + kcol + k_src;
    unsigned short* dst = lbuf + half * 8192 + j * 4096 + wave * 512;  // wave-uniform base
    __builtin_amdgcn_global_load_lds((const __attribute__((address_space(1))) void*)src,
                                     (__attribute__((address_space(3))) void*)dst, 16, 0, 0);
  }
}

#define BAR() do { asm volatile("" ::: "memory"); __builtin_amdgcn_s_barrier(); \
                   asm volatile("" ::: "memory"); } while (0)
#define LGKM0() asm volatile("s_waitcnt lgkmcnt(0)" ::: "memory")
#define VMC(n) asm volatile("s_waitcnt vmcnt(" #n ")" ::: "memory")

#define READ_A(qr) \
  _Pragma("unroll") for (int i4 = 0; i4 < 4; ++i4) \
  _Pragma("unroll") for (int ks = 0; ks < 2; ++ks) { \
    const int r_ = wrow + (qr) * 64 + i4 * 16 + fr; \
    a[i4][ks] = *(const short8*)(Abase + r_ * 128 + ((ks * 64 + kq16) ^ flip)); }

#define READ_B(qc) \
  _Pragma("unroll") for (int c2 = 0; c2 < 2; ++c2) \
  _Pragma("unroll") for (int ks = 0; ks < 2; ++ks) { \
    const int c_ = wcol + (qc) * 32 + c2 * 16 + fr; \
    b[qc][c2][ks] = *(const short8*)(Bbase + c_ * 128 + ((ks * 64 + kq16) ^ flip)); }

#define DO_MFMA(qr, qc) \
  _Pragma("unroll") for (int i4 = 0; i4 < 4; ++i4) \
  _Pragma("unroll") for (int c2 = 0; c2 < 2; ++c2) \
  _Pragma("unroll") for (int ks = 0; ks < 2; ++ks) \
    acc[(qr) * 4 + i4][(qc) * 2 + c2] = __builtin_amdgcn_mfma_f32_16x16x32_bf16( \
        a[i4][ks], b[qc][c2][ks], acc[(qr) * 4 + i4][(qc) * 2 + c2], 0, 0, 0);

template<int EPI>
__global__ __launch_bounds__(512, 2) void gemm256(
    const unsigned short* __restrict__ A, const unsigned short* __restrict__ Bt,
    const float* __restrict__ bias0, const float* __restrict__ bias1,
    const float* __restrict__ bias2,
    float* __restrict__ outF,
    unsigned short* __restrict__ oQ, unsigned short* __restrict__ oK,
    unsigned short* __restrict__ oV,
    int M, int N, int K)
{
  __shared__ alignas(16) unsigned short As[2][16384];
  __shared__ alignas(16) unsigned short Bs[2][16384];
  const int tid  = threadIdx.x;
  const int lane = tid & 63;
  const int wave = tid >> 6;
  const int wr = wave >> 2, wc = wave & 3;
  const int fr   = lane & 15;
  const int kq16 = (lane >> 4) * 16;
  const int flip = (fr & 7) << 4;
  const int nwg = gridDim.x, cpx = nwg >> 3, orig = blockIdx.x;
  const int logical = (orig & 7) * cpx + (orig >> 3);
  const int ntc = N >> 8;
  const int brow = (logical / ntc) << 8;
  const int bcol = (logical % ntc) << 8;
  const int NT = K >> 6;
  const int wrow = wr * 128, wcol = wc * 64;

  f32x4 acc[8][4] = {};
  short8 a[4][2], b[2][2][2];

  // prologue: tile0 {A0,A1,B0,B1}, tile1 {B0,A0}
  stage_half(A,  brow, K, 0, &As[0][0], 0, wave, lane);
  stage_half(A,  brow, K, 0, &As[0][0], 1, wave, lane);
  stage_half(Bt, bcol, K, 0, &Bs[0][0], 0, wave, lane);
  stage_half(Bt, bcol, K, 0, &Bs[0][0], 1, wave, lane);
  if (NT > 1) {
    stage_half(Bt, bcol, K, 64, &Bs[1][0], 0, wave, lane);
    stage_half(A,  brow, K, 64, &As[1][0], 0, wave, lane);
    VMC(4);
  } else {
    VMC(0);
  }
  BAR();

  for (int t = 0; t < NT; ++t) {
    const int cur = t & 1;
    const char* Abase = (const char*)&As[cur][0];
    const char* Bbase = (const char*)&Bs[cur][0];
    const int k1 = (t + 1) << 6, k2 = (t + 2) << 6;

    READ_A(0)
    READ_B(0)
    if (t < NT - 1) stage_half(Bt, bcol, K, k1, &Bs[cur ^ 1][0], 1, wave, lane);
    BAR(); LGKM0();
    __builtin_amdgcn_s_setprio(1);
    DO_MFMA(0, 0)
    __builtin_amdgcn_s_setprio(0);
    BAR();

    READ_B(1)
    if (t < NT - 1) stage_half(A, brow, K, k1, &As[cur ^ 1][0], 1, wave, lane);
    BAR(); LGKM0();
    __builtin_amdgcn_s_setprio(1);
    DO_MFMA(0, 1)
    __builtin_amdgcn_s_setprio(0);
    BAR();

    READ_A(1)
    if (t < NT - 2) stage_half(Bt, bcol, K, k2, &Bs[cur][0], 0, wave, lane);
    BAR(); LGKM0();
    __builtin_amdgcn_s_setprio(1);
    DO_MFMA(1, 0)
    __builtin_amdgcn_s_setprio(0);
    BAR();

    if (t < NT - 2) stage_half(A, brow, K, k2, &As[cur][0], 0, wave, lane);
    BAR();
    __builtin_amdgcn_s_setprio(1);
    DO_MFMA(1, 1)
    __builtin_amdgcn_s_setprio(0);
    if (t < NT - 2)      { VMC(4); }
    else if (t < NT - 1) { VMC(0); }
    BAR();
  }

  // epilogue: C/D layout col=lane&15, row=(lane>>4)*4+q  [m89 verified]
  // EPI==0 writes row-major [rr][1024] per output matrix (contiguous 32B chunks)
  const int l4 = (lane >> 4) * 4;
#pragma unroll
  for (int rg = 0; rg < 8; ++rg) {
    const int row0 = brow + wrow + rg * 16 + l4;
#pragma unroll
    for (int cg = 0; cg < 4; ++cg) {
      const int col = bcol + wcol + cg * 16 + fr;
      if (EPI == 1) {
        const float bb = bias0[col];
#pragma unroll
        for (int q = 0; q < 4; ++q)
          outF[(size_t)(row0 + q) * N + col] = acc[rg][cg][q] + bb;
      } else {
        const int sel = col >> 10;        // 0=q, 1=k, 2=v
        const int o = col & 1023;
        const float* bp = (sel == 0) ? bias0 : (sel == 1) ? bias1 : bias2;
        unsigned short* dstp = (sel == 0) ? oQ : (sel == 1) ? oK : oV;
        const float bb = bp[o];
#pragma unroll
        for (int q = 0; q < 4; ++q) {
          float val = acc[rg][cg][q] + bb;
          if (sel < 2) val = (val > 0.f) ? (val + 1.f) : __expf(val);  // elu(x)+1
          dstp[(size_t)(row0 + q) * 1024 + o] = f2bf(val);
        }
      }
    }
  }
}

// ---------------- kv partials (bf16): grid 1024 = 64 bh x 16 chunks of 256 s ----------------
__global__ __launch_bounds__(256) void kv_agg(
    const unsigned short* __restrict__ kbuf, const unsigned short* __restrict__ vbuf,
    unsigned short* __restrict__ part_kv, float* __restrict__ part_ks)
{
  __shared__ alignas(16) unsigned short Ksm[16 * 64];
  __shared__ alignas(16) unsigned short Vsm[16 * 64];
  const int blk = blockIdx.x;           // 0..1023
  const int bh = blk >> 4, chunk = blk & 15;
  const int bb = bh >> 4, h = bh & 15;
  const int t = threadIdx.x;
  const int d0 = (t >> 4) * 4;
  const int e0 = (t & 15) * 4;
  const int ls = (t & 127) >> 3;
  const int lc = (t & 7) * 8;
  float acc[4][4] = {};
  float ks[4] = {0.f, 0.f, 0.f, 0.f};
  const int rb = bb * 4096 + chunk * 256;
  for (int ss = 0; ss < 256; ss += 16) {
    __syncthreads();
    const size_t ga = (size_t)(rb + ss + ls) * 1024 + h * 64 + lc;
    if (t < 128) *(uint4*)&Ksm[ls * 64 + lc] = *(const uint4*)&kbuf[ga];
    else         *(uint4*)&Vsm[ls * 64 + lc] = *(const uint4*)&vbuf[ga];
    __syncthreads();
#pragma unroll
    for (int i = 0; i < 16; ++i) {
      const unsigned ku0 = *(const unsigned*)&Ksm[i * 64 + d0];
      const unsigned ku1 = *(const unsigned*)&Ksm[i * 64 + d0 + 2];
      const unsigned vu0 = *(const unsigned*)&Vsm[i * 64 + e0];
      const unsigned vu1 = *(const unsigned*)&Vsm[i * 64 + e0 + 2];
      const float kk0 = __uint_as_float(ku0 << 16), kk1 = __uint_as_float(ku0 & 0xFFFF0000u);
      const float kk2 = __uint_as_float(ku1 << 16), kk3 = __uint_as_float(ku1 & 0xFFFF0000u);
      const float vv0 = __uint_as_float(vu0 << 16), vv1 = __uint_as_float(vu0 & 0xFFFF0000u);
      const float vv2 = __uint_as_float(vu1 << 16), vv3 = __uint_as_float(vu1 & 0xFFFF0000u);
      ks[0] += kk0; ks[1] += kk1; ks[2] += kk2; ks[3] += kk3;
      acc[0][0] += kk0 * vv0; acc[0][1] += kk0 * vv1; acc[0][2] += kk0 * vv2; acc[0][3] += kk0 * vv3;
      acc[1][0] += kk1 * vv0; acc[1][1] += kk1 * vv1; acc[1][2] += kk1 * vv2; acc[1][3] += kk1 * vv3;
      acc[2][0] += kk2 * vv0; acc[2][1] += kk2 * vv1; acc[2][2] += kk2 * vv2; acc[2][3] += kk2 * vv3;
      acc[3][0] += kk3 * vv0; acc[3][1] += kk3 * vv1; acc[3][2] += kk3 * vv2; acc[3][3] += kk3 * vv3;
    }
  }
#pragma unroll
  for (int r = 0; r < 4; ++r) {
    const unsigned lo = (unsigned)f2bf(acc[r][0]) | ((unsigned)f2bf(acc[r][1]) << 16);
    const unsigned hi = (unsigned)f2bf(acc[r][2]) | ((unsigned)f2bf(acc[r][3]) << 16);
    *(uint2*)&part_kv[((size_t)blk * 64 + d0 + r) * 64 + e0] = make_uint2(lo, hi);
  }
  if ((t & 15) == 0) {
#pragma unroll
    for (int r = 0; r < 4; ++r) part_ks[blk * 64 + d0 + r] = ks[r];
  }
}

// ------- collapse bf16 partials -> kvTb bf16 [bh][e][d] + ksum f32 [bh][64] -------
__global__ __launch_bounds__(256) void kv_reduce(
    const unsigned short* __restrict__ part_kv, const float* __restrict__ part_ks,
    unsigned short* __restrict__ kvTb, float* __restrict__ ksf)
{
  const int bh = blockIdx.x;            // 64
  const int t = threadIdx.x;
#pragma unroll
  for (int i = 0; i < 16; ++i) {
    const int lin = i * 256 + t;        // lin = d*64+e
    float s = 0.f;
#pragma unroll
    for (int c = 0; c < 16; ++c) s += bf2f(part_kv[((size_t)(bh * 16 + c)) * 4096 + lin]);
    const int d = lin >> 6, e = lin & 63;
    kvTb[(size_t)bh * 4096 + e * 64 + d] = f2bf(s);   // transposed bf16
  }
  if (t < 64) {
    float s = 0.f;
#pragma unroll
    for (int c = 0; c < 16; ++c) s += part_ks[(bh * 16 + c) * 64 + t];
    ksf[bh * 64 + t] = s;
  }
}

// ---------------- attn via MFMA: C = q_tile(256x64) . kvT, normalized ----------------
__global__ __launch_bounds__(256) void attn_mfma(
    const unsigned short* __restrict__ qbuf,   // [rr][1024]
    const unsigned short* __restrict__ kvTb,   // [bh][e][d] bf16
    const float* __restrict__ ksf,             // [bh][64]
    unsigned short* __restrict__ attnb)        // [rr][1024]
{
  __shared__ alignas(16) unsigned short kvs[64 * 64];  // swizzled: 16B slot ^= e&7
  __shared__ float ks_lds[64];
  __shared__ float inv_lds[256];
  const int blk = blockIdx.x;           // 1024 = bh*16 + ntile
  const int bh = blk >> 4, ntile = blk & 15;
  const int bb = bh >> 4, h = bh & 15;
  const int t = threadIdx.x;
  const int lane = t & 63, w = t >> 6;
  const int fr = lane & 15, kg = lane >> 4;

  {
    const unsigned short* src = kvTb + (size_t)bh * 4096;
#pragma unroll
    for (int c = 0; c < 2; ++c) {
      const int slot = t * 2 + c;
      const int e = slot >> 3, sl = slot & 7;
      short8 v = *(const short8*)&src[e * 64 + sl * 8];
      *(short8*)&kvs[e * 64 + (sl ^ (e & 7)) * 8] = v;
    }
    if (t < 64) ks_lds[t] = ksf[bh * 64 + t];
  }

  const size_t gq = (size_t)bb * 4096 + ntile * 256 + w * 64;
  short8 a[4][2];
#pragma unroll
  for (int rg = 0; rg < 4; ++rg)
#pragma unroll
    for (int ks = 0; ks < 2; ++ks)
      a[rg][ks] = *(const short8*)&qbuf[(gq + rg * 16 + fr) * 1024 + h * 64 + ks * 32 + kg * 8];
  __syncthreads();

#pragma unroll
  for (int rg = 0; rg < 4; ++rg) {
    float p = 0.f;
#pragma unroll
    for (int ks = 0; ks < 2; ++ks)
#pragma unroll
      for (int j = 0; j < 8; ++j)
        p += bf2f(((const unsigned short*)&a[rg][ks])[j]) * ks_lds[ks * 32 + kg * 8 + j];
    p += __shfl_xor(p, 16);
    p += __shfl_xor(p, 32);
    if (kg == 0) inv_lds[w * 64 + rg * 16 + fr] = 1.f / (p + 1e-6f);
  }

  const int flip = (fr & 7) << 4;
  const int kq16 = kg * 16;
  short8 bf[4][2];
#pragma unroll
  for (int cg = 0; cg < 4; ++cg)
#pragma unroll
    for (int ks = 0; ks < 2; ++ks)
      bf[cg][ks] = *(const short8*)((const char*)kvs + (cg * 16 + fr) * 128 + ((ks * 64 + kq16) ^ flip));
  f32x4 acc[4][4] = {};
#pragma unroll
  for (int rg = 0; rg < 4; ++rg)
#pragma unroll
    for (int cg = 0; cg < 4; ++cg)
#pragma unroll
      for (int ks = 0; ks < 2; ++ks)
        acc[rg][cg] = __builtin_amdgcn_mfma_f32_16x16x32_bf16(a[rg][ks], bf[cg][ks], acc[rg][cg], 0, 0, 0);

  __syncthreads();

#pragma unroll
  for (int rg = 0; rg < 4; ++rg)
#pragma unroll
    for (int cg = 0; cg < 4; ++cg)
#pragma unroll
      for (int q = 0; q < 4; ++q) {
        const int r = rg * 16 + kg * 4 + q;
        const float iv = inv_lds[w * 64 + r];
        attnb[(gq + r) * 1024 + h * 64 + cg * 16 + fr] = f2bf(acc[rg][cg][q] * iv);
      }
}

extern "C" void kernel_launch(void* const* d_in, const int* in_sizes, int n_in,
                              void* d_out, int out_size, void* d_ws, size_t ws_size,
                              hipStream_t stream)
{
  const float* query = (const float*)d_in[0];
  const float* Wq = (const float*)d_in[1];
  const float* bq = (const float*)d_in[2];
  const float* Wk = (const float*)d_in[3];
  const float* bk = (const float*)d_in[4];
  const float* Wv = (const float*)d_in[5];
  const float* bv = (const float*)d_in[6];
  const float* Wo = (const float*)d_in[7];
  const float* bo = (const float*)d_in[8];
  float* out = (float*)d_out;

  const int M = in_sizes[0] / 1024;               // 16384 rows (B*N)

  char* ws = (char*)d_ws;
  unsigned short* qbf   = (unsigned short*)(ws);              // 32MB (dead after QKV)
  unsigned short* attnb = (unsigned short*)(ws);              // reuse
  unsigned short* wqkv  = (unsigned short*)(ws + 33554432);   // 6MB
  unsigned short* wobf  = (unsigned short*)(ws + 39845888);   // 2MB
  unsigned short* phiq  = (unsigned short*)(ws + 41943040);   // 32MB [rr][1024]
  unsigned short* phik  = (unsigned short*)(ws + 75497472);   // 32MB
  unsigned short* vbf   = (unsigned short*)(ws + 109051904);  // 32MB
  unsigned short* pkv   = (unsigned short*)(ws + 142606336);  // 8MB bf16 [1024][64][64]
  float*          pks   = (float*)(ws + 159383552);           // 256KB
  unsigned short* kvTb  = (unsigned short*)(ws + 159645696);  // 512KB [64][64][64]
  float*          ksf   = (float*)(ws + 160169984);           // 16KB

  // 1) all casts, one launch (16384 query blocks + 4096 weight blocks)
  cast_all<<<20480, 256, 0, stream>>>(query, Wq, Wk, Wv, Wo,
                                      qbf, wqkv, wqkv + 1048576, wqkv + 2097152, wobf);

  // 2) fused QKV projection + feature map (grid 768 = 96/XCD)
  gemm256<0><<<dim3((M / 256) * (3072 / 256)), 512, 0, stream>>>(
      qbf, wqkv, bq, bk, bv, nullptr, phiq, phik, vbf, M, 3072, 1024);

  kv_agg<<<1024, 256, 0, stream>>>(phik, vbf, pkv, pks);
  kv_reduce<<<64, 256, 0, stream>>>(pkv, pks, kvTb, ksf);
  attn_mfma<<<1024, 256, 0, stream>>>(phiq, kvTb, ksf, attnb);

  // 6) output projection -> fp32 d_out (grid 256 = 32/XCD)
  gemm256<1><<<dim3((M / 256) * (1024 / 256)), 512, 0, stream>>>(
      attnb, wobf, bo, nullptr, nullptr, out, nullptr, nullptr, nullptr, M, 1024, 1024);
}

// Round 15
// 239.921 us; speedup vs baseline: 1.1140x; 1.0065x over previous
//
#include <hip/hip_runtime.h>

typedef __attribute__((ext_vector_type(8))) short short8;   // 8 bf16 = 4 VGPRs
typedef __attribute__((ext_vector_type(4))) float f32x4;    // MFMA accumulator

#define DEV static __device__ __forceinline__

DEV float bf2f(unsigned short b) { return __uint_as_float(((unsigned)b) << 16); }
DEV unsigned short f2bf(float f) {                          // round-to-nearest-even
  unsigned u = __float_as_uint(f);
  u += 0x7FFFu + ((u >> 16) & 1u);
  return (unsigned short)(u >> 16);
}

#if __has_builtin(__builtin_amdgcn_fdot2_f32_bf16)
#define HAVE_DOT2 1
typedef __attribute__((ext_vector_type(2))) __bf16 bf16x2;
DEV float dot2bf(unsigned a, unsigned b, float c) {
  bf16x2 av, bv;
  __builtin_memcpy(&av, &a, 4);
  __builtin_memcpy(&bv, &b, 4);
  return __builtin_amdgcn_fdot2_f32_bf16(av, bv, c, false);
}
#endif

// ---------------- prep: all f32 -> bf16 casts in ONE launch ----------------
// query: 16384x1024 f32 = 4,194,304 float4 -> 16384 blocks of 256
// weights: 4 x 1024x1024 f32 = 262,144 float4 each -> 4 x 1024 blocks
__global__ __launch_bounds__(256) void cast_all(
    const float* __restrict__ q,
    const float* __restrict__ w0, const float* __restrict__ w1,
    const float* __restrict__ w2, const float* __restrict__ w3,
    unsigned short* __restrict__ oq,
    unsigned short* __restrict__ o0, unsigned short* __restrict__ o1,
    unsigned short* __restrict__ o2, unsigned short* __restrict__ o3) {
  const int b = blockIdx.x;
  const float* s;
  unsigned short* d;
  int i;
  if (b < 16384) {                        // query
    s = q; d = oq; i = b * 256 + threadIdx.x;
  } else {                                // weights
    const int wsel = (b - 16384) >> 10, wb = (b - 16384) & 1023;
    s = (wsel == 0) ? w0 : (wsel == 1) ? w1 : (wsel == 2) ? w2 : w3;
    d = (wsel == 0) ? o0 : (wsel == 1) ? o1 : (wsel == 2) ? o2 : o3;
    i = wb * 256 + threadIdx.x;
  }
  float4 f = ((const float4*)s)[i];
  unsigned lo = (unsigned)f2bf(f.x) | ((unsigned)f2bf(f.y) << 16);
  unsigned hi = (unsigned)f2bf(f.z) | ((unsigned)f2bf(f.w) << 16);
  ((uint2*)d)[i] = make_uint2(lo, hi);
}

// ============== 256x256 8-phase bf16 GEMM (r7 schedule — best measured) ==============
DEV void stage_half(const unsigned short* __restrict__ g, int row0, int ldk, int kcol,
                    unsigned short* lbuf, int half, int wave, int lane) {
#pragma unroll
  for (int j = 0; j < 2; ++j) {
    const int row_lin = half * 128 + j * 64 + wave * 8 + (lane >> 3);
    const int k_src = (((lane & 7) ^ ((lane >> 3) & 7)) * 8);  // 16B slot ^= row&7
    const unsigned short* src = g + (size_t)(row0 + row_lin) * ldk + kcol + k_src;
    unsigned short* dst = lbuf + half * 8192 + j * 4096 + wave * 512;  // wave-uniform base
    __builtin_amdgcn_global_load_lds((const __attribute__((address_space(1))) void*)src,
                                     (__attribute__((address_space(3))) void*)dst, 16, 0, 0);
  }
}

#define BAR() do { asm volatile("" ::: "memory"); __builtin_amdgcn_s_barrier(); \
                   asm volatile("" ::: "memory"); } while (0)
#define LGKM0() asm volatile("s_waitcnt lgkmcnt(0)" ::: "memory")
#define VMC(n) asm volatile("s_waitcnt vmcnt(" #n ")" ::: "memory")

#define READ_A(qr) \
  _Pragma("unroll") for (int i4 = 0; i4 < 4; ++i4) \
  _Pragma("unroll") for (int ks = 0; ks < 2; ++ks) { \
    const int r_ = wrow + (qr) * 64 + i4 * 16 + fr; \
    a[i4][ks] = *(const short8*)(Abase + r_ * 128 + ((ks * 64 + kq16) ^ flip)); }

#define READ_B(qc) \
  _Pragma("unroll") for (int c2 = 0; c2 < 2; ++c2) \
  _Pragma("unroll") for (int ks = 0; ks < 2; ++ks) { \
    const int c_ = wcol + (qc) * 32 + c2 * 16 + fr; \
    b[qc][c2][ks] = *(const short8*)(Bbase + c_ * 128 + ((ks * 64 + kq16) ^ flip)); }

#define DO_MFMA(qr, qc) \
  _Pragma("unroll") for (int i4 = 0; i4 < 4; ++i4) \
  _Pragma("unroll") for (int c2 = 0; c2 < 2; ++c2) \
  _Pragma("unroll") for (int ks = 0; ks < 2; ++ks) \
    acc[(qr) * 4 + i4][(qc) * 2 + c2] = __builtin_amdgcn_mfma_f32_16x16x32_bf16( \
        a[i4][ks], b[qc][c2][ks], acc[(qr) * 4 + i4][(qc) * 2 + c2], 0, 0, 0);

template<int EPI>
__global__ __launch_bounds__(512, 2) void gemm256(
    const unsigned short* __restrict__ A, const unsigned short* __restrict__ Bt,
    const float* __restrict__ bias0, const float* __restrict__ bias1,
    const float* __restrict__ bias2,
    float* __restrict__ outF,
    unsigned short* __restrict__ oQ, unsigned short* __restrict__ oK,
    unsigned short* __restrict__ oV,
    int M, int N, int K)
{
  __shared__ alignas(16) unsigned short As[2][16384];
  __shared__ alignas(16) unsigned short Bs[2][16384];
  const int tid  = threadIdx.x;
  const int lane = tid & 63;
  const int wave = tid >> 6;
  const int wr = wave >> 2, wc = wave & 3;
  const int fr   = lane & 15;
  const int kq16 = (lane >> 4) * 16;
  const int flip = (fr & 7) << 4;
  const int nwg = gridDim.x, cpx = nwg >> 3, orig = blockIdx.x;
  const int logical = (orig & 7) * cpx + (orig >> 3);
  const int ntc = N >> 8;
  const int brow = (logical / ntc) << 8;
  const int bcol = (logical % ntc) << 8;
  const int NT = K >> 6;
  const int wrow = wr * 128, wcol = wc * 64;

  f32x4 acc[8][4] = {};
  short8 a[4][2], b[2][2][2];

  // prologue: tile0 {A0,A1,B0,B1}, tile1 {B0,A0}
  stage_half(A,  brow, K, 0, &As[0][0], 0, wave, lane);
  stage_half(A,  brow, K, 0, &As[0][0], 1, wave, lane);
  stage_half(Bt, bcol, K, 0, &Bs[0][0], 0, wave, lane);
  stage_half(Bt, bcol, K, 0, &Bs[0][0], 1, wave, lane);
  if (NT > 1) {
    stage_half(Bt, bcol, K, 64, &Bs[1][0], 0, wave, lane);
    stage_half(A,  brow, K, 64, &As[1][0], 0, wave, lane);
    VMC(4);
  } else {
    VMC(0);
  }
  BAR();

  for (int t = 0; t < NT; ++t) {
    const int cur = t & 1;
    const char* Abase = (const char*)&As[cur][0];
    const char* Bbase = (const char*)&Bs[cur][0];
    const int k1 = (t + 1) << 6, k2 = (t + 2) << 6;

    READ_A(0)
    READ_B(0)
    if (t < NT - 1) stage_half(Bt, bcol, K, k1, &Bs[cur ^ 1][0], 1, wave, lane);
    BAR(); LGKM0();
    __builtin_amdgcn_s_setprio(1);
    DO_MFMA(0, 0)
    __builtin_amdgcn_s_setprio(0);
    BAR();

    READ_B(1)
    if (t < NT - 1) stage_half(A, brow, K, k1, &As[cur ^ 1][0], 1, wave, lane);
    BAR(); LGKM0();
    __builtin_amdgcn_s_setprio(1);
    DO_MFMA(0, 1)
    __builtin_amdgcn_s_setprio(0);
    BAR();

    READ_A(1)
    if (t < NT - 2) stage_half(Bt, bcol, K, k2, &Bs[cur][0], 0, wave, lane);
    BAR(); LGKM0();
    __builtin_amdgcn_s_setprio(1);
    DO_MFMA(1, 0)
    __builtin_amdgcn_s_setprio(0);
    BAR();

    if (t < NT - 2) stage_half(A, brow, K, k2, &As[cur][0], 0, wave, lane);
    BAR();
    __builtin_amdgcn_s_setprio(1);
    DO_MFMA(1, 1)
    __builtin_amdgcn_s_setprio(0);
    if (t < NT - 2)      { VMC(4); }
    else if (t < NT - 1) { VMC(0); }
    BAR();
  }

  // epilogue: C/D layout col=lane&15, row=(lane>>4)*4+q  [m89 verified]
  // EPI==0 writes row-major [rr][1024] per output matrix (contiguous 32B chunks)
  const int l4 = (lane >> 4) * 4;
#pragma unroll
  for (int rg = 0; rg < 8; ++rg) {
    const int row0 = brow + wrow + rg * 16 + l4;
#pragma unroll
    for (int cg = 0; cg < 4; ++cg) {
      const int col = bcol + wcol + cg * 16 + fr;
      if (EPI == 1) {
        const float bb = bias0[col];
#pragma unroll
        for (int q = 0; q < 4; ++q)
          outF[(size_t)(row0 + q) * N + col] = acc[rg][cg][q] + bb;
      } else {
        const int sel = col >> 10;        // 0=q, 1=k, 2=v
        const int o = col & 1023;
        const float* bp = (sel == 0) ? bias0 : (sel == 1) ? bias1 : bias2;
        unsigned short* dstp = (sel == 0) ? oQ : (sel == 1) ? oK : oV;
        const float bb = bp[o];
#pragma unroll
        for (int q = 0; q < 4; ++q) {
          float val = acc[rg][cg][q] + bb;
          if (sel < 2) val = (val > 0.f) ? (val + 1.f) : __expf(val);  // elu(x)+1
          dstp[(size_t)(row0 + q) * 1024 + o] = f2bf(val);
        }
      }
    }
  }
}

// ---------------- kv partials (bf16): grid 1024 = 64 bh x 16 chunks of 256 s ----------------
// dot2 path: pair 2 s-rows per iter via v_perm_b32, accumulate with v_dot2_f32_bf16
__global__ __launch_bounds__(256) void kv_agg(
    const unsigned short* __restrict__ kbuf, const unsigned short* __restrict__ vbuf,
    unsigned short* __restrict__ part_kv, float* __restrict__ part_ks)
{
  __shared__ alignas(16) unsigned short Ksm[16 * 64];
  __shared__ alignas(16) unsigned short Vsm[16 * 64];
  const int blk = blockIdx.x;           // 0..1023
  const int bh = blk >> 4, chunk = blk & 15;
  const int bb = bh >> 4, h = bh & 15;
  const int t = threadIdx.x;
  const int d0 = (t >> 4) * 4;
  const int e0 = (t & 15) * 4;
  const int ls = (t & 127) >> 3;
  const int lc = (t & 7) * 8;
  float acc[4][4] = {};
  float ks[4] = {0.f, 0.f, 0.f, 0.f};
  const int rb = bb * 4096 + chunk * 256;
  for (int ss = 0; ss < 256; ss += 16) {
    __syncthreads();
    const size_t ga = (size_t)(rb + ss + ls) * 1024 + h * 64 + lc;
    if (t < 128) *(uint4*)&Ksm[ls * 64 + lc] = *(const uint4*)&kbuf[ga];
    else         *(uint4*)&Vsm[ls * 64 + lc] = *(const uint4*)&vbuf[ga];
    __syncthreads();
#ifdef HAVE_DOT2
#pragma unroll
    for (int i = 0; i < 16; i += 2) {
      const unsigned ka0 = *(const unsigned*)&Ksm[i * 64 + d0];
      const unsigned ka1 = *(const unsigned*)&Ksm[i * 64 + d0 + 2];
      const unsigned kb0 = *(const unsigned*)&Ksm[(i + 1) * 64 + d0];
      const unsigned kb1 = *(const unsigned*)&Ksm[(i + 1) * 64 + d0 + 2];
      const unsigned va0 = *(const unsigned*)&Vsm[i * 64 + e0];
      const unsigned va1 = *(const unsigned*)&Vsm[i * 64 + e0 + 2];
      const unsigned vb0 = *(const unsigned*)&Vsm[(i + 1) * 64 + e0];
      const unsigned vb1 = *(const unsigned*)&Vsm[(i + 1) * 64 + e0 + 2];
      unsigned pk[4], pv[4];
      pk[0] = __builtin_amdgcn_perm(kb0, ka0, 0x05040100u);   // (k[i,d0], k[i+1,d0])
      pk[1] = __builtin_amdgcn_perm(kb0, ka0, 0x07060302u);   // d0+1
      pk[2] = __builtin_amdgcn_perm(kb1, ka1, 0x05040100u);   // d0+2
      pk[3] = __builtin_amdgcn_perm(kb1, ka1, 0x07060302u);   // d0+3
      pv[0] = __builtin_amdgcn_perm(vb0, va0, 0x05040100u);
      pv[1] = __builtin_amdgcn_perm(vb0, va0, 0x07060302u);
      pv[2] = __builtin_amdgcn_perm(vb1, va1, 0x05040100u);
      pv[3] = __builtin_amdgcn_perm(vb1, va1, 0x07060302u);
#pragma unroll
      for (int r = 0; r < 4; ++r) {
        ks[r] = dot2bf(pk[r], 0x3F803F80u, ks[r]);            // + k[i,d]+k[i+1,d]
#pragma unroll
        for (int c = 0; c < 4; ++c) acc[r][c] = dot2bf(pk[r], pv[c], acc[r][c]);
      }
    }
#else
#pragma unroll
    for (int i = 0; i < 16; ++i) {
      const unsigned ku0 = *(const unsigned*)&Ksm[i * 64 + d0];
      const unsigned ku1 = *(const unsigned*)&Ksm[i * 64 + d0 + 2];
      const unsigned vu0 = *(const unsigned*)&Vsm[i * 64 + e0];
      const unsigned vu1 = *(const unsigned*)&Vsm[i * 64 + e0 + 2];
      const float kk0 = __uint_as_float(ku0 << 16), kk1 = __uint_as_float(ku0 & 0xFFFF0000u);
      const float kk2 = __uint_as_float(ku1 << 16), kk3 = __uint_as_float(ku1 & 0xFFFF0000u);
      const float vv0 = __uint_as_float(vu0 << 16), vv1 = __uint_as_float(vu0 & 0xFFFF0000u);
      const float vv2 = __uint_as_float(vu1 << 16), vv3 = __uint_as_float(vu1 & 0xFFFF0000u);
      ks[0] += kk0; ks[1] += kk1; ks[2] += kk2; ks[3] += kk3;
      acc[0][0] += kk0 * vv0; acc[0][1] += kk0 * vv1; acc[0][2] += kk0 * vv2; acc[0][3] += kk0 * vv3;
      acc[1][0] += kk1 * vv0; acc[1][1] += kk1 * vv1; acc[1][2] += kk1 * vv2; acc[1][3] += kk1 * vv3;
      acc[2][0] += kk2 * vv0; acc[2][1] += kk2 * vv1; acc[2][2] += kk2 * vv2; acc[2][3] += kk2 * vv3;
      acc[3][0] += kk3 * vv0; acc[3][1] += kk3 * vv1; acc[3][2] += kk3 * vv2; acc[3][3] += kk3 * vv3;
    }
#endif
  }
#pragma unroll
  for (int r = 0; r < 4; ++r) {
    const unsigned lo = (unsigned)f2bf(acc[r][0]) | ((unsigned)f2bf(acc[r][1]) << 16);
    const unsigned hi = (unsigned)f2bf(acc[r][2]) | ((unsigned)f2bf(acc[r][3]) << 16);
    *(uint2*)&part_kv[((size_t)blk * 64 + d0 + r) * 64 + e0] = make_uint2(lo, hi);
  }
  if ((t & 15) == 0) {
#pragma unroll
    for (int r = 0; r < 4; ++r) part_ks[blk * 64 + d0 + r] = ks[r];
  }
}

// ------- collapse bf16 partials -> kvTb bf16 [bh][e][d] + ksum f32 [bh][64] -------
__global__ __launch_bounds__(256) void kv_reduce(
    const unsigned short* __restrict__ part_kv, const float* __restrict__ part_ks,
    unsigned short* __restrict__ kvTb, float* __restrict__ ksf)
{
  const int bh = blockIdx.x;            // 64
  const int t = threadIdx.x;
#pragma unroll
  for (int i = 0; i < 16; ++i) {
    const int lin = i * 256 + t;        // lin = d*64+e
    float s = 0.f;
#pragma unroll
    for (int c = 0; c < 16; ++c) s += bf2f(part_kv[((size_t)(bh * 16 + c)) * 4096 + lin]);
    const int d = lin >> 6, e = lin & 63;
    kvTb[(size_t)bh * 4096 + e * 64 + d] = f2bf(s);   // transposed bf16
  }
  if (t < 64) {
    float s = 0.f;
#pragma unroll
    for (int c = 0; c < 16; ++c) s += part_ks[(bh * 16 + c) * 64 + t];
    ksf[bh * 64 + t] = s;
  }
}

// ---------------- attn via MFMA: C = q_tile(256x64) . kvT, normalized ----------------
__global__ __launch_bounds__(256) void attn_mfma(
    const unsigned short* __restrict__ qbuf,   // [rr][1024]
    const unsigned short* __restrict__ kvTb,   // [bh][e][d] bf16
    const float* __restrict__ ksf,             // [bh][64]
    unsigned short* __restrict__ attnb)        // [rr][1024]
{
  __shared__ alignas(16) unsigned short kvs[64 * 64];  // swizzled: 16B slot ^= e&7
  __shared__ float ks_lds[64];
  __shared__ float inv_lds[256];
  const int blk = blockIdx.x;           // 1024 = bh*16 + ntile
  const int bh = blk >> 4, ntile = blk & 15;
  const int bb = bh >> 4, h = bh & 15;
  const int t = threadIdx.x;
  const int lane = t & 63, w = t >> 6;
  const int fr = lane & 15, kg = lane >> 4;

  {
    const unsigned short* src = kvTb + (size_t)bh * 4096;
#pragma unroll
    for (int c = 0; c < 2; ++c) {
      const int slot = t * 2 + c;
      const int e = slot >> 3, sl = slot & 7;
      short8 v = *(const short8*)&src[e * 64 + sl * 8];
      *(short8*)&kvs[e * 64 + (sl ^ (e & 7)) * 8] = v;
    }
    if (t < 64) ks_lds[t] = ksf[bh * 64 + t];
  }

  const size_t gq = (size_t)bb * 4096 + ntile * 256 + w * 64;
  short8 a[4][2];
#pragma unroll
  for (int rg = 0; rg < 4; ++rg)
#pragma unroll
    for (int ks = 0; ks < 2; ++ks)
      a[rg][ks] = *(const short8*)&qbuf[(gq + rg * 16 + fr) * 1024 + h * 64 + ks * 32 + kg * 8];
  __syncthreads();

#pragma unroll
  for (int rg = 0; rg < 4; ++rg) {
    float p = 0.f;
#pragma unroll
    for (int ks = 0; ks < 2; ++ks)
#pragma unroll
      for (int j = 0; j < 8; ++j)
        p += bf2f(((const unsigned short*)&a[rg][ks])[j]) * ks_lds[ks * 32 + kg * 8 + j];
    p += __shfl_xor(p, 16);
    p += __shfl_xor(p, 32);
    if (kg == 0) inv_lds[w * 64 + rg * 16 + fr] = 1.f / (p + 1e-6f);
  }

  const int flip = (fr & 7) << 4;
  const int kq16 = kg * 16;
  short8 bf[4][2];
#pragma unroll
  for (int cg = 0; cg < 4; ++cg)
#pragma unroll
    for (int ks = 0; ks < 2; ++ks)
      bf[cg][ks] = *(const short8*)((const char*)kvs + (cg * 16 + fr) * 128 + ((ks * 64 + kq16) ^ flip));
  f32x4 acc[4][4] = {};
#pragma unroll
  for (int rg = 0; rg < 4; ++rg)
#pragma unroll
    for (int cg = 0; cg < 4; ++cg)
#pragma unroll
      for (int ks = 0; ks < 2; ++ks)
        acc[rg][cg] = __builtin_amdgcn_mfma_f32_16x16x32_bf16(a[rg][ks], bf[cg][ks], acc[rg][cg], 0, 0, 0);

  __syncthreads();

#pragma unroll
  for (int rg = 0; rg < 4; ++rg)
#pragma unroll
    for (int cg = 0; cg < 4; ++cg)
#pragma unroll
      for (int q = 0; q < 4; ++q) {
        const int r = rg * 16 + kg * 4 + q;
        const float iv = inv_lds[w * 64 + r];
        attnb[(gq + r) * 1024 + h * 64 + cg * 16 + fr] = f2bf(acc[rg][cg][q] * iv);
      }
}

extern "C" void kernel_launch(void* const* d_in, const int* in_sizes, int n_in,
                              void* d_out, int out_size, void* d_ws, size_t ws_size,
                              hipStream_t stream)
{
  const float* query = (const float*)d_in[0];
  const float* Wq = (const float*)d_in[1];
  const float* bq = (const float*)d_in[2];
  const float* Wk = (const float*)d_in[3];
  const float* bk = (const float*)d_in[4];
  const float* Wv = (const float*)d_in[5];
  const float* bv = (const float*)d_in[6];
  const float* Wo = (const float*)d_in[7];
  const float* bo = (const float*)d_in[8];
  float* out = (float*)d_out;

  const int M = in_sizes[0] / 1024;               // 16384 rows (B*N)

  char* ws = (char*)d_ws;
  unsigned short* qbf   = (unsigned short*)(ws);              // 32MB (dead after QKV)
  unsigned short* attnb = (unsigned short*)(ws);              // reuse
  unsigned short* wqkv  = (unsigned short*)(ws + 33554432);   // 6MB
  unsigned short* wobf  = (unsigned short*)(ws + 39845888);   // 2MB
  unsigned short* phiq  = (unsigned short*)(ws + 41943040);   // 32MB [rr][1024]
  unsigned short* phik  = (unsigned short*)(ws + 75497472);   // 32MB
  unsigned short* vbf   = (unsigned short*)(ws + 109051904);  // 32MB
  unsigned short* pkv   = (unsigned short*)(ws + 142606336);  // 8MB bf16 [1024][64][64]
  float*          pks   = (float*)(ws + 159383552);           // 256KB
  unsigned short* kvTb  = (unsigned short*)(ws + 159645696);  // 512KB [64][64][64]
  float*          ksf   = (float*)(ws + 160169984);           // 16KB

  // 1) all casts, one launch (16384 query blocks + 4096 weight blocks)
  cast_all<<<20480, 256, 0, stream>>>(query, Wq, Wk, Wv, Wo,
                                      qbf, wqkv, wqkv + 1048576, wqkv + 2097152, wobf);

  // 2) fused QKV projection + feature map (grid 768 = 96/XCD)
  gemm256<0><<<dim3((M / 256) * (3072 / 256)), 512, 0, stream>>>(
      qbf, wqkv, bq, bk, bv, nullptr, phiq, phik, vbf, M, 3072, 1024);

  kv_agg<<<1024, 256, 0, stream>>>(phik, vbf, pkv, pks);
  kv_reduce<<<64, 256, 0, stream>>>(pkv, pks, kvTb, ksf);
  attn_mfma<<<1024, 256, 0, stream>>>(phiq, kvTb, ksf, attnb);

  // 6) output projection -> fp32 d_out (grid 256 = 32/XCD)
  gemm256<1><<<dim3((M / 256) * (1024 / 256)), 512, 0, stream>>>(
      attnb, wobf, bo, nullptr, nullptr, out, nullptr, nullptr, nullptr, M, 1024, 1024);
}

// Round 16
// 231.907 us; speedup vs baseline: 1.1525x; 1.0346x over previous
//
#include <hip/hip_runtime.h>

typedef __attribute__((ext_vector_type(8))) short short8;   // 8 bf16 = 4 VGPRs
typedef __attribute__((ext_vector_type(4))) float f32x4;    // MFMA accumulator

#define DEV static __device__ __forceinline__

DEV float bf2f(unsigned short b) { return __uint_as_float(((unsigned)b) << 16); }
DEV unsigned short f2bf(float f) {                          // round-to-nearest-even
  unsigned u = __float_as_uint(f);
  u += 0x7FFFu + ((u >> 16) & 1u);
  return (unsigned short)(u >> 16);
}

#if __has_builtin(__builtin_amdgcn_fdot2_f32_bf16)
#define HAVE_DOT2 1
typedef __attribute__((ext_vector_type(2))) __bf16 bf16x2;
DEV float dot2bf(unsigned a, unsigned b, float c) {
  bf16x2 av, bv;
  __builtin_memcpy(&av, &a, 4);
  __builtin_memcpy(&bv, &b, 4);
  return __builtin_amdgcn_fdot2_f32_bf16(av, bv, c, false);
}
#endif

// ---------------- prep: all f32 -> bf16 casts in ONE launch ----------------
__global__ __launch_bounds__(256) void cast_all(
    const float* __restrict__ q,
    const float* __restrict__ w0, const float* __restrict__ w1,
    const float* __restrict__ w2, const float* __restrict__ w3,
    unsigned short* __restrict__ oq,
    unsigned short* __restrict__ o0, unsigned short* __restrict__ o1,
    unsigned short* __restrict__ o2, unsigned short* __restrict__ o3) {
  const int b = blockIdx.x;
  const float* s;
  unsigned short* d;
  int i;
  if (b < 16384) {                        // query: 4,194,304 float4
    s = q; d = oq; i = b * 256 + threadIdx.x;
  } else {                                // weights: 4 x 262,144 float4
    const int wsel = (b - 16384) >> 10, wb = (b - 16384) & 1023;
    s = (wsel == 0) ? w0 : (wsel == 1) ? w1 : (wsel == 2) ? w2 : w3;
    d = (wsel == 0) ? o0 : (wsel == 1) ? o1 : (wsel == 2) ? o2 : o3;
    i = wb * 256 + threadIdx.x;
  }
  float4 f = ((const float4*)s)[i];
  unsigned lo = (unsigned)f2bf(f.x) | ((unsigned)f2bf(f.y) << 16);
  unsigned hi = (unsigned)f2bf(f.z) | ((unsigned)f2bf(f.w) << 16);
  ((uint2*)d)[i] = make_uint2(lo, hi);
}

// ============== 256x256 8-phase bf16 GEMM (r7 schedule — best measured) ==============
DEV void stage_half(const unsigned short* __restrict__ g, int row0, int ldk, int kcol,
                    unsigned short* lbuf, int half, int wave, int lane) {
#pragma unroll
  for (int j = 0; j < 2; ++j) {
    const int row_lin = half * 128 + j * 64 + wave * 8 + (lane >> 3);
    const int k_src = (((lane & 7) ^ ((lane >> 3) & 7)) * 8);  // 16B slot ^= row&7
    const unsigned short* src = g + (size_t)(row0 + row_lin) * ldk + kcol + k_src;
    unsigned short* dst = lbuf + half * 8192 + j * 4096 + wave * 512;  // wave-uniform base
    __builtin_amdgcn_global_load_lds((const __attribute__((address_space(1))) void*)src,
                                     (__attribute__((address_space(3))) void*)dst, 16, 0, 0);
  }
}

#define BAR() do { asm volatile("" ::: "memory"); __builtin_amdgcn_s_barrier(); \
                   asm volatile("" ::: "memory"); } while (0)
#define LGKM0() asm volatile("s_waitcnt lgkmcnt(0)" ::: "memory")
#define VMC(n) asm volatile("s_waitcnt vmcnt(" #n ")" ::: "memory")

#define READ_A(qr) \
  _Pragma("unroll") for (int i4 = 0; i4 < 4; ++i4) \
  _Pragma("unroll") for (int ks = 0; ks < 2; ++ks) { \
    const int r_ = wrow + (qr) * 64 + i4 * 16 + fr; \
    a[i4][ks] = *(const short8*)(Abase + r_ * 128 + ((ks * 64 + kq16) ^ flip)); }

#define READ_B(qc) \
  _Pragma("unroll") for (int c2 = 0; c2 < 2; ++c2) \
  _Pragma("unroll") for (int ks = 0; ks < 2; ++ks) { \
    const int c_ = wcol + (qc) * 32 + c2 * 16 + fr; \
    b[qc][c2][ks] = *(const short8*)(Bbase + c_ * 128 + ((ks * 64 + kq16) ^ flip)); }

#define DO_MFMA(qr, qc) \
  _Pragma("unroll") for (int i4 = 0; i4 < 4; ++i4) \
  _Pragma("unroll") for (int c2 = 0; c2 < 2; ++c2) \
  _Pragma("unroll") for (int ks = 0; ks < 2; ++ks) \
    acc[(qr) * 4 + i4][(qc) * 2 + c2] = __builtin_amdgcn_mfma_f32_16x16x32_bf16( \
        a[i4][ks], b[qc][c2][ks], acc[(qr) * 4 + i4][(qc) * 2 + c2], 0, 0, 0);

template<int EPI>
__global__ __launch_bounds__(512, 2) void gemm256(
    const unsigned short* __restrict__ A, const unsigned short* __restrict__ Bt,
    const float* __restrict__ bias0, const float* __restrict__ bias1,
    const float* __restrict__ bias2,
    float* __restrict__ outF,
    unsigned short* __restrict__ oQ, unsigned short* __restrict__ oK,
    unsigned short* __restrict__ oV,
    int M, int N, int K)
{
  __shared__ alignas(16) unsigned short As[2][16384];
  __shared__ alignas(16) unsigned short Bs[2][16384];
  const int tid  = threadIdx.x;
  const int lane = tid & 63;
  const int wave = tid >> 6;
  const int wr = wave >> 2, wc = wave & 3;
  const int fr   = lane & 15;
  const int kq16 = (lane >> 4) * 16;
  const int flip = (fr & 7) << 4;
  const int nwg = gridDim.x, cpx = nwg >> 3, orig = blockIdx.x;
  const int logical = (orig & 7) * cpx + (orig >> 3);
  const int ntc = N >> 8;
  const int brow = (logical / ntc) << 8;
  const int bcol = (logical % ntc) << 8;
  const int NT = K >> 6;
  const int wrow = wr * 128, wcol = wc * 64;

  f32x4 acc[8][4] = {};
  short8 a[4][2], b[2][2][2];

  // prologue: tile0 {A0,A1,B0,B1}, tile1 {B0,A0}
  stage_half(A,  brow, K, 0, &As[0][0], 0, wave, lane);
  stage_half(A,  brow, K, 0, &As[0][0], 1, wave, lane);
  stage_half(Bt, bcol, K, 0, &Bs[0][0], 0, wave, lane);
  stage_half(Bt, bcol, K, 0, &Bs[0][0], 1, wave, lane);
  if (NT > 1) {
    stage_half(Bt, bcol, K, 64, &Bs[1][0], 0, wave, lane);
    stage_half(A,  brow, K, 64, &As[1][0], 0, wave, lane);
    VMC(4);
  } else {
    VMC(0);
  }
  BAR();

  for (int t = 0; t < NT; ++t) {
    const int cur = t & 1;
    const char* Abase = (const char*)&As[cur][0];
    const char* Bbase = (const char*)&Bs[cur][0];
    const int k1 = (t + 1) << 6, k2 = (t + 2) << 6;

    READ_A(0)
    READ_B(0)
    if (t < NT - 1) stage_half(Bt, bcol, K, k1, &Bs[cur ^ 1][0], 1, wave, lane);
    BAR(); LGKM0();
    __builtin_amdgcn_s_setprio(1);
    DO_MFMA(0, 0)
    __builtin_amdgcn_s_setprio(0);
    BAR();

    READ_B(1)
    if (t < NT - 1) stage_half(A, brow, K, k1, &As[cur ^ 1][0], 1, wave, lane);
    BAR(); LGKM0();
    __builtin_amdgcn_s_setprio(1);
    DO_MFMA(0, 1)
    __builtin_amdgcn_s_setprio(0);
    BAR();

    READ_A(1)
    if (t < NT - 2) stage_half(Bt, bcol, K, k2, &Bs[cur][0], 0, wave, lane);
    BAR(); LGKM0();
    __builtin_amdgcn_s_setprio(1);
    DO_MFMA(1, 0)
    __builtin_amdgcn_s_setprio(0);
    BAR();

    if (t < NT - 2) stage_half(A, brow, K, k2, &As[cur][0], 0, wave, lane);
    BAR();
    __builtin_amdgcn_s_setprio(1);
    DO_MFMA(1, 1)
    __builtin_amdgcn_s_setprio(0);
    if (t < NT - 2)      { VMC(4); }
    else if (t < NT - 1) { VMC(0); }
    BAR();
  }

  // epilogue: C/D layout col=lane&15, row=(lane>>4)*4+q  [m89 verified]
  const int l4 = (lane >> 4) * 4;
#pragma unroll
  for (int rg = 0; rg < 8; ++rg) {
    const int row0 = brow + wrow + rg * 16 + l4;
#pragma unroll
    for (int cg = 0; cg < 4; ++cg) {
      const int col = bcol + wcol + cg * 16 + fr;
      if (EPI == 1) {
        const float bb = bias0[col];
#pragma unroll
        for (int q = 0; q < 4; ++q)
          outF[(size_t)(row0 + q) * N + col] = acc[rg][cg][q] + bb;
      } else {
        const int sel = col >> 10;        // 0=q, 1=k, 2=v
        const int o = col & 1023;
        const float* bp = (sel == 0) ? bias0 : (sel == 1) ? bias1 : bias2;
        unsigned short* dstp = (sel == 0) ? oQ : (sel == 1) ? oK : oV;
        const float bb = bp[o];
#pragma unroll
        for (int q = 0; q < 4; ++q) {
          float val = acc[rg][cg][q] + bb;
          if (sel < 2) val = (val > 0.f) ? (val + 1.f) : __expf(val);  // elu(x)+1
          dstp[(size_t)(row0 + q) * 1024 + o] = f2bf(val);
        }
      }
    }
  }
}

// ---------------- kv partials (bf16): grid 1024 = 64 bh x 16 chunks of 256 s ----------------
__global__ __launch_bounds__(256) void kv_agg(
    const unsigned short* __restrict__ kbuf, const unsigned short* __restrict__ vbuf,
    unsigned short* __restrict__ part_kv, float* __restrict__ part_ks)
{
  __shared__ alignas(16) unsigned short Ksm[16 * 64];
  __shared__ alignas(16) unsigned short Vsm[16 * 64];
  const int blk = blockIdx.x;           // 0..1023
  const int bh = blk >> 4, chunk = blk & 15;
  const int bb = bh >> 4, h = bh & 15;
  const int t = threadIdx.x;
  const int d0 = (t >> 4) * 4;
  const int e0 = (t & 15) * 4;
  const int ls = (t & 127) >> 3;
  const int lc = (t & 7) * 8;
  float acc[4][4] = {};
  float ks[4] = {0.f, 0.f, 0.f, 0.f};
  const int rb = bb * 4096 + chunk * 256;
  for (int ss = 0; ss < 256; ss += 16) {
    __syncthreads();
    const size_t ga = (size_t)(rb + ss + ls) * 1024 + h * 64 + lc;
    if (t < 128) *(uint4*)&Ksm[ls * 64 + lc] = *(const uint4*)&kbuf[ga];
    else         *(uint4*)&Vsm[ls * 64 + lc] = *(const uint4*)&vbuf[ga];
    __syncthreads();
#ifdef HAVE_DOT2
#pragma unroll
    for (int i = 0; i < 16; i += 2) {
      const unsigned ka0 = *(const unsigned*)&Ksm[i * 64 + d0];
      const unsigned ka1 = *(const unsigned*)&Ksm[i * 64 + d0 + 2];
      const unsigned kb0 = *(const unsigned*)&Ksm[(i + 1) * 64 + d0];
      const unsigned kb1 = *(const unsigned*)&Ksm[(i + 1) * 64 + d0 + 2];
      const unsigned va0 = *(const unsigned*)&Vsm[i * 64 + e0];
      const unsigned va1 = *(const unsigned*)&Vsm[i * 64 + e0 + 2];
      const unsigned vb0 = *(const unsigned*)&Vsm[(i + 1) * 64 + e0];
      const unsigned vb1 = *(const unsigned*)&Vsm[(i + 1) * 64 + e0 + 2];
      unsigned pk[4], pv[4];
      pk[0] = __builtin_amdgcn_perm(kb0, ka0, 0x05040100u);
      pk[1] = __builtin_amdgcn_perm(kb0, ka0, 0x07060302u);
      pk[2] = __builtin_amdgcn_perm(kb1, ka1, 0x05040100u);
      pk[3] = __builtin_amdgcn_perm(kb1, ka1, 0x07060302u);
      pv[0] = __builtin_amdgcn_perm(vb0, va0, 0x05040100u);
      pv[1] = __builtin_amdgcn_perm(vb0, va0, 0x07060302u);
      pv[2] = __builtin_amdgcn_perm(vb1, va1, 0x05040100u);
      pv[3] = __builtin_amdgcn_perm(vb1, va1, 0x07060302u);
#pragma unroll
      for (int r = 0; r < 4; ++r) {
        ks[r] = dot2bf(pk[r], 0x3F803F80u, ks[r]);
#pragma unroll
        for (int c = 0; c < 4; ++c) acc[r][c] = dot2bf(pk[r], pv[c], acc[r][c]);
      }
    }
#else
#pragma unroll
    for (int i = 0; i < 16; ++i) {
      const unsigned ku0 = *(const unsigned*)&Ksm[i * 64 + d0];
      const unsigned ku1 = *(const unsigned*)&Ksm[i * 64 + d0 + 2];
      const unsigned vu0 = *(const unsigned*)&Vsm[i * 64 + e0];
      const unsigned vu1 = *(const unsigned*)&Vsm[i * 64 + e0 + 2];
      const float kk0 = __uint_as_float(ku0 << 16), kk1 = __uint_as_float(ku0 & 0xFFFF0000u);
      const float kk2 = __uint_as_float(ku1 << 16), kk3 = __uint_as_float(ku1 & 0xFFFF0000u);
      const float vv0 = __uint_as_float(vu0 << 16), vv1 = __uint_as_float(vu0 & 0xFFFF0000u);
      const float vv2 = __uint_as_float(vu1 << 16), vv3 = __uint_as_float(vu1 & 0xFFFF0000u);
      ks[0] += kk0; ks[1] += kk1; ks[2] += kk2; ks[3] += kk3;
      acc[0][0] += kk0 * vv0; acc[0][1] += kk0 * vv1; acc[0][2] += kk0 * vv2; acc[0][3] += kk0 * vv3;
      acc[1][0] += kk1 * vv0; acc[1][1] += kk1 * vv1; acc[1][2] += kk1 * vv2; acc[1][3] += kk1 * vv3;
      acc[2][0] += kk2 * vv0; acc[2][1] += kk2 * vv1; acc[2][2] += kk2 * vv2; acc[2][3] += kk2 * vv3;
      acc[3][0] += kk3 * vv0; acc[3][1] += kk3 * vv1; acc[3][2] += kk3 * vv2; acc[3][3] += kk3 * vv3;
    }
#endif
  }
#pragma unroll
  for (int r = 0; r < 4; ++r) {
    const unsigned lo = (unsigned)f2bf(acc[r][0]) | ((unsigned)f2bf(acc[r][1]) << 16);
    const unsigned hi = (unsigned)f2bf(acc[r][2]) | ((unsigned)f2bf(acc[r][3]) << 16);
    *(uint2*)&part_kv[((size_t)blk * 64 + d0 + r) * 64 + e0] = make_uint2(lo, hi);
  }
  if ((t & 15) == 0) {
#pragma unroll
    for (int r = 0; r < 4; ++r) part_ks[blk * 64 + d0 + r] = ks[r];
  }
}

// ------- attn via MFMA with FUSED 16-way partial reduce (kv_reduce folded in) -------
// Per block: reduce part_kv[bh*16..+16][d][e] (L2/L3-hot, 128KB) into swizzled LDS [e][d],
// reduce part_ks into ks_lds; then C = q_tile(256x64) . kvT, normalized, as before.
__global__ __launch_bounds__(256) void attn_fused(
    const unsigned short* __restrict__ qbuf,   // [rr][1024]
    const unsigned short* __restrict__ part_kv,// [1024][64][64] bf16
    const float* __restrict__ part_ks,         // [1024][64]
    unsigned short* __restrict__ attnb)        // [rr][1024]
{
  __shared__ alignas(16) unsigned short kvs[64 * 64];  // [e][d], 16B slot ^= e&7
  __shared__ float ks_lds[64];
  __shared__ float inv_lds[256];
  const int blk = blockIdx.x;           // 1024 = bh*16 + ntile
  const int bh = blk >> 4, ntile = blk & 15;
  const int bb = bh >> 4, h = bh & 15;
  const int t = threadIdx.x;
  const int lane = t & 63, w = t >> 6;
  const int fr = lane & 15, kg = lane >> 4;

  // ---- fused reduce: thread owns row d = t>>2, e-range (t&3)*16..+15 ----
  {
    const int d = t >> 2, e0 = (t & 3) * 16;
    float s[16] = {};
    const unsigned short* base = part_kv + ((size_t)bh * 16) * 4096 + d * 64 + e0;
#pragma unroll
    for (int c = 0; c < 16; ++c) {
      short8 v0 = *(const short8*)(base + (size_t)c * 4096);
      short8 v1 = *(const short8*)(base + (size_t)c * 4096 + 8);
#pragma unroll
      for (int j = 0; j < 8; ++j) {
        s[j]     += bf2f(((const unsigned short*)&v0)[j]);
        s[8 + j] += bf2f(((const unsigned short*)&v1)[j]);
      }
    }
    const int sl = d >> 3, dw = d & 7;         // d's 16B slot / word within slot
#pragma unroll
    for (int j = 0; j < 16; ++j) {
      const int e = e0 + j;
      kvs[e * 64 + ((sl ^ (e & 7)) * 8) + dw] = f2bf(s[j]);   // transposed + swizzled
    }
    if (t < 64) {
      float ss = 0.f;
#pragma unroll
      for (int c = 0; c < 16; ++c) ss += part_ks[(bh * 16 + c) * 64 + t];
      ks_lds[t] = ss;
    }
  }

  // ---- q fragments from global (no LDS dependency) ----
  const size_t gq = (size_t)bb * 4096 + ntile * 256 + w * 64;
  short8 a[4][2];
#pragma unroll
  for (int rg = 0; rg < 4; ++rg)
#pragma unroll
    for (int ks = 0; ks < 2; ++ks)
      a[rg][ks] = *(const short8*)&qbuf[(gq + rg * 16 + fr) * 1024 + h * 64 + ks * 32 + kg * 8];
  __syncthreads();

  // ---- denominator ----
#pragma unroll
  for (int rg = 0; rg < 4; ++rg) {
    float p = 0.f;
#pragma unroll
    for (int ks = 0; ks < 2; ++ks)
#pragma unroll
      for (int j = 0; j < 8; ++j)
        p += bf2f(((const unsigned short*)&a[rg][ks])[j]) * ks_lds[ks * 32 + kg * 8 + j];
    p += __shfl_xor(p, 16);
    p += __shfl_xor(p, 32);
    if (kg == 0) inv_lds[w * 64 + rg * 16 + fr] = 1.f / (p + 1e-6f);
  }

  // ---- kv fragments + MFMA ----
  const int flip = (fr & 7) << 4;
  const int kq16 = kg * 16;
  short8 bf[4][2];
#pragma unroll
  for (int cg = 0; cg < 4; ++cg)
#pragma unroll
    for (int ks = 0; ks < 2; ++ks)
      bf[cg][ks] = *(const short8*)((const char*)kvs + (cg * 16 + fr) * 128 + ((ks * 64 + kq16) ^ flip));
  f32x4 acc[4][4] = {};
#pragma unroll
  for (int rg = 0; rg < 4; ++rg)
#pragma unroll
    for (int cg = 0; cg < 4; ++cg)
#pragma unroll
      for (int ks = 0; ks < 2; ++ks)
        acc[rg][cg] = __builtin_amdgcn_mfma_f32_16x16x32_bf16(a[rg][ks], bf[cg][ks], acc[rg][cg], 0, 0, 0);

  __syncthreads();   // inv_lds visible

#pragma unroll
  for (int rg = 0; rg < 4; ++rg)
#pragma unroll
    for (int cg = 0; cg < 4; ++cg)
#pragma unroll
      for (int q = 0; q < 4; ++q) {
        const int r = rg * 16 + kg * 4 + q;
        const float iv = inv_lds[w * 64 + r];
        attnb[(gq + r) * 1024 + h * 64 + cg * 16 + fr] = f2bf(acc[rg][cg][q] * iv);
      }
}

extern "C" void kernel_launch(void* const* d_in, const int* in_sizes, int n_in,
                              void* d_out, int out_size, void* d_ws, size_t ws_size,
                              hipStream_t stream)
{
  const float* query = (const float*)d_in[0];
  const float* Wq = (const float*)d_in[1];
  const float* bq = (const float*)d_in[2];
  const float* Wk = (const float*)d_in[3];
  const float* bk = (const float*)d_in[4];
  const float* Wv = (const float*)d_in[5];
  const float* bv = (const float*)d_in[6];
  const float* Wo = (const float*)d_in[7];
  const float* bo = (const float*)d_in[8];
  float* out = (float*)d_out;

  const int M = in_sizes[0] / 1024;               // 16384 rows (B*N)

  char* ws = (char*)d_ws;
  unsigned short* qbf   = (unsigned short*)(ws);              // 32MB (dead after QKV)
  unsigned short* attnb = (unsigned short*)(ws);              // reuse
  unsigned short* wqkv  = (unsigned short*)(ws + 33554432);   // 6MB
  unsigned short* wobf  = (unsigned short*)(ws + 39845888);   // 2MB
  unsigned short* phiq  = (unsigned short*)(ws + 41943040);   // 32MB [rr][1024]
  unsigned short* phik  = (unsigned short*)(ws + 75497472);   // 32MB
  unsigned short* vbf   = (unsigned short*)(ws + 109051904);  // 32MB
  unsigned short* pkv   = (unsigned short*)(ws + 142606336);  // 8MB bf16 [1024][64][64]
  float*          pks   = (float*)(ws + 159383552);           // 256KB

  // 1) all casts, one launch
  cast_all<<<20480, 256, 0, stream>>>(query, Wq, Wk, Wv, Wo,
                                      qbf, wqkv, wqkv + 1048576, wqkv + 2097152, wobf);

  // 2) fused QKV projection + feature map (grid 768 = 96/XCD)
  gemm256<0><<<dim3((M / 256) * (3072 / 256)), 512, 0, stream>>>(
      qbf, wqkv, bq, bk, bv, nullptr, phiq, phik, vbf, M, 3072, 1024);

  // 3) kv partials
  kv_agg<<<1024, 256, 0, stream>>>(phik, vbf, pkv, pks);

  // 4) attn with fused partial-reduce -> bf16 [16384,1024] (into old qbf region)
  attn_fused<<<1024, 256, 0, stream>>>(phiq, pkv, pks, attnb);

  // 5) output projection -> fp32 d_out (grid 256 = 32/XCD)
  gemm256<1><<<dim3((M / 256) * (1024 / 256)), 512, 0, stream>>>(
      attnb, wobf, bo, nullptr, nullptr, out, nullptr, nullptr, nullptr, M, 1024, 1024);
}